// Round 27
// baseline (393.979 us; speedup 1.0000x reference)
//
#include <hip/hip_runtime.h>
#include <cstdint>
#include <cstddef>

// Problem constants
#define NB 2
#define NT 8192
#define ND 1024
#define NH 4
#define NV 1024
#define NHV 256
#define NHK 128
#define CHK 64
#define NCHK 128            // chunks per (b,h)
#define QKS 1024            // merged q|k row stride
#define VGS 2048            // merged v|g row stride
#define SCALE 0.08838834764831845f   // HK^-0.5

using f32x4 = __attribute__((ext_vector_type(4))) float;
using short8 = __attribute__((ext_vector_type(8))) short;
using s16x4 = __attribute__((ext_vector_type(4))) short;

__device__ __forceinline__ float bf2f(unsigned short u){
  union { unsigned int i; float f; } t; t.i = ((unsigned int)u) << 16; return t.f;
}
__device__ __forceinline__ unsigned short f2bf(float f){
  union { float f; unsigned int i; } t; t.f = f;
  unsigned int r = t.i + 0x7fffu + ((t.i >> 16) & 1u);
  return (unsigned short)(r >> 16);
}
__device__ __forceinline__ double shfl_up_dbl(double v, int off){
  union { double d; unsigned int u[2]; } a, r;
  a.d = v;
  r.u[0] = __shfl_up(a.u[0], off, 64);
  r.u[1] = __shfl_up(a.u[1], off, 64);
  return r.d;
}
// Swizzled LDS accessor for bf16 tiles: row-major, rowBytes in {128,256}.
__device__ __forceinline__ void* lds_at(void* base, int row, int colElem, int rowBytes){
  return (void*)((char*)base + row*rowBytes + (((colElem*2) ^ ((row&7)<<4))));
}
// swizzle for the [64][256] bf16 o-tile (512B rows)
__device__ __forceinline__ int osw(int rowl, int byteoff){
  return rowl*512 + (byteoff ^ (((rowl>>2)&7)<<4));
}
// XCD-chunked, A-panel-major block swizzle. total = gx*gy must be %8==0.
__device__ __forceinline__ void xcd_swizzle(int gx, int gy, int& bx, int& by){
  int flat = blockIdx.y*gx + blockIdx.x;
  int total = gx*gy;
  int wg = (flat & 7)*(total >> 3) + (flat >> 3);
  bx = wg / gy;
  by = wg % gy;
}

// ---- async global->LDS, 16B per lane; dest is wave-uniform base + lane*16 (m97 pattern) ----
typedef const __attribute__((address_space(1))) unsigned int as1_u32;
typedef __attribute__((address_space(3))) unsigned int as3_u32;
__device__ __forceinline__ void gl_lds16(const void* g_lane, void* lds_uniform){
  __builtin_amdgcn_global_load_lds((as1_u32*)(uintptr_t)g_lane,
                                   (as3_u32*)(unsigned int)(uintptr_t)lds_uniform,
                                   16, 0, 0);
}

// ---- fused prep: blocks 0..16383 = alphacast; 16384..17407 = LDS-tiled weight transposes ----
__global__ __launch_bounds__(256) void k_prep(const float* __restrict__ hs,
                                              const float* __restrict__ Wa,
                                              const float* __restrict__ Al,
                                              const float* __restrict__ dtb,
                                              float* __restrict__ Gc,
                                              unsigned short* __restrict__ hsh,
                                              const float* __restrict__ Wq,
                                              const float* __restrict__ Wk,
                                              const float* __restrict__ Wv,
                                              const float* __restrict__ Wg,
                                              const float* __restrict__ Wo,
                                              unsigned short* __restrict__ wqkh,
                                              unsigned short* __restrict__ wqkl,
                                              unsigned short* __restrict__ wvgt,
                                              unsigned short* __restrict__ wot){
  int b = blockIdx.x, tid = threadIdx.x;
  if (b < 16384){
    // ---- alphacast: cast hs row to bf16 + alpha = hs@Wa -> gk (pre-cumsum, exact fp32) ----
    int rowi = b;
    const float* h = hs + (size_t)rowi*ND;
    f32x4 x = *(const f32x4*)(h + tid*4);
    s16x4 hb;
    #pragma unroll
    for (int e=0;e<4;e++) hb[e] = (short)f2bf(x[e]);
    *(s16x4*)(hsh + (size_t)rowi*ND + tid*4) = hb;
    float a0=0.f,a1=0.f,a2=0.f,a3=0.f;
    #pragma unroll
    for (int e=0;e<4;e++){
      int d = tid*4+e;
      a0 += x[e]*Wa[d*4+0]; a1 += x[e]*Wa[d*4+1]; a2 += x[e]*Wa[d*4+2]; a3 += x[e]*Wa[d*4+3];
    }
    #pragma unroll
    for (int off=32; off>0; off>>=1){
      a0 += __shfl_down(a0, off, 64); a1 += __shfl_down(a1, off, 64);
      a2 += __shfl_down(a2, off, 64); a3 += __shfl_down(a3, off, 64);
    }
    __shared__ float red[4][4];
    if ((tid&63)==0){ int w = tid>>6; red[w][0]=a0; red[w][1]=a1; red[w][2]=a2; red[w][3]=a3; }
    __syncthreads();
    if (tid < 4){
      float al = red[0][tid]+red[1][tid]+red[2][tid]+red[3][tid];
      float xx = al + dtb[tid];
      float sp = (xx > 20.f) ? xx : log1pf(expf(xx));
      float gkv = -expf(Al[tid]) * sp;
      int bb = rowi >> 13, t = rowi & (NT-1);
      Gc[((size_t)(bb*NH + tid))*NT + t] = gkv;
    }
  } else {
    // ---- LDS-tiled 64x64 transpose: coalesced reads AND writes ----
    __shared__ float tile[64][65];
    int b2 = b - 16384;
    const float* src; int C; int rt, ct; int hilo = 0; size_t boff = 0;
    unsigned short *dsth = nullptr, *dstl = nullptr;
    if (b2 < 128){          src = Wq; C = 512;  rt = b2 >> 3;          ct = b2 & 7;  hilo = 1; boff = 0;          dsth = wqkh; dstl = wqkl; }
    else if (b2 < 256){     src = Wk; C = 512;  rt = (b2-128) >> 3;    ct = (b2-128) & 7;  hilo = 1; boff = 512*1024;  dsth = wqkh; dstl = wqkl; }
    else if (b2 < 512){     src = Wv; C = 1024; rt = (b2-256) >> 4;    ct = (b2-256) & 15; boff = 0;          dsth = wvgt; }
    else if (b2 < 768){     src = Wg; C = 1024; rt = (b2-512) >> 4;    ct = (b2-512) & 15; boff = 1024*1024; dsth = wvgt; }
    else {                  src = Wo; C = 1024; rt = (b2-768) >> 4;    ct = (b2-768) & 15; boff = 0;          dsth = wot;  }
    int r0 = rt*64, c0 = ct*64;
    #pragma unroll
    for (int it=0; it<16; ++it){
      int r = it*4 + (tid>>6);
      int c = tid & 63;
      tile[r][c] = src[(size_t)(r0+r)*C + c0 + c];
    }
    __syncthreads();
    #pragma unroll
    for (int it=0; it<16; ++it){
      int c = it*4 + (tid>>6);
      int r = tid & 63;
      float x = tile[r][c];
      unsigned short h = f2bf(x);
      dsth[boff + (size_t)(c0+c)*1024 + r0 + r] = h;
      if (hilo) dstl[boff + (size_t)(c0+c)*1024 + r0 + r] = f2bf(x - bf2f(h));
    }
  }
}

// --- 2-phase dbuf GEMM: C = A@Bth^T (+A@Btl^T if BSPLIT) ---
// GSWISH: 0 = none; 2 = swish where n0 >= 1024 (merged v|g output).
template<int BSPLIT, int GSWISH>
__global__ __launch_bounds__(256, BSPLIT ? 3 : 4)
void k_gemm2(const unsigned short* __restrict__ A2h,
             const unsigned short* __restrict__ Bth,
             const unsigned short* __restrict__ Btl,
             unsigned short* __restrict__ C, int M, int N, int K){
  __shared__ unsigned short sA[2][4096];
  __shared__ unsigned short sB[2][4096];
  __shared__ unsigned short sBl[BSPLIT ? 2*4096 : 8];
  int tid = threadIdx.x, lane = tid & 63, wave = tid >> 6;
  int bx, by;
  xcd_swizzle(gridDim.x, gridDim.y, bx, by);
  int m0 = bx*128, n0 = by*128;
  int wr = (wave>>1)*64, wc = (wave&1)*64;
  int row = lane & 15, kq = (lane>>4)*8;
  int rS = lane>>2, cS = (lane&3)*8;
  f32x4 acc[4][4];
  #pragma unroll
  for (int m=0;m<4;m++)
    #pragma unroll
    for (int n=0;n<4;n++)
      #pragma unroll
      for (int r=0;r<4;r++) acc[m][n][r] = 0.f;

  auto STAGE = [&](int buf, int k0){
    #pragma unroll
    for (int half=0; half<2; ++half){
      int rb = half*64 + wave*16;
      size_t gArow = (size_t)(m0 + rb + rS)*K + k0 + cS;
      size_t gBrow = (size_t)(n0 + rb + rS)*K + k0 + cS;
      gl_lds16(A2h + gArow, &sA[buf][rb*32]);
      gl_lds16(Bth + gBrow, &sB[buf][rb*32]);
      if (BSPLIT) gl_lds16(Btl + gBrow, &sBl[buf*4096 + rb*32]);
    }
  };

  STAGE(0, 0);
  __syncthreads();
  int nsteps = K >> 5;
  for (int t=0; t<nsteps; ++t){
    int cur = t & 1;
    if (t+1 < nsteps) STAGE(cur^1, (t+1)*32);
    short8 ah[4], bh[4];
    #pragma unroll
    for (int m=0;m<4;m++) ah[m] = *(const short8*)(&sA[cur][(wr + m*16 + row)*32 + kq]);
    #pragma unroll
    for (int n=0;n<4;n++) bh[n] = *(const short8*)(&sB[cur][(wc + n*16 + row)*32 + kq]);
    #pragma unroll
    for (int m=0;m<4;m++)
      #pragma unroll
      for (int n=0;n<4;n++)
        acc[m][n] = __builtin_amdgcn_mfma_f32_16x16x32_bf16(ah[m], bh[n], acc[m][n], 0, 0, 0);
    if (BSPLIT){
      short8 bl[4];
      #pragma unroll
      for (int n=0;n<4;n++) bl[n] = *(const short8*)(&sBl[cur*4096 + (wc + n*16 + row)*32 + kq]);
      #pragma unroll
      for (int m=0;m<4;m++)
        #pragma unroll
        for (int n=0;n<4;n++)
          acc[m][n] = __builtin_amdgcn_mfma_f32_16x16x32_bf16(ah[m], bl[n], acc[m][n], 0, 0, 0);
    }
    __syncthreads();
  }
  bool dosw = (GSWISH == 2) && (n0 >= 1024);
  #pragma unroll
  for (int m=0;m<4;m++)
    #pragma unroll
    for (int n=0;n<4;n++)
      #pragma unroll
      for (int r=0;r<4;r++){
        int rr = m0 + wr + m*16 + (lane>>4)*4 + r;
        int cc = n0 + wc + n*16 + (lane&15);
        float v = acc[m][n][r];
        if (dosw) v = v / (1.f + expf(-v));
        C[(size_t)rr*N + cc] = f2bf(v);
      }
}

// ---------------- final GEMM (fp32 out), dbuf prefetch, strided A ----------------
__global__ __launch_bounds__(256, 4) void k_gemm(const unsigned short* __restrict__ A,
                                                 const unsigned short* __restrict__ Bt,
                                                 float* __restrict__ C, int M, int N, int K,
                                                 int lda){
  __shared__ unsigned short sA[2][4096];
  __shared__ unsigned short sB[2][4096];
  int tid = threadIdx.x, lane = tid & 63, wave = tid >> 6;
  int bx, by;
  xcd_swizzle(gridDim.x, gridDim.y, bx, by);
  int m0 = bx*128, n0 = by*128;
  int wr = (wave>>1)*64, wc = (wave&1)*64;
  int row = lane & 15, kq = (lane>>4)*8;
  int rS = lane>>2, cS = (lane&3)*8;
  f32x4 acc[4][4];
  #pragma unroll
  for (int m=0;m<4;m++)
    #pragma unroll
    for (int n=0;n<4;n++)
      #pragma unroll
      for (int r=0;r<4;r++) acc[m][n][r] = 0.f;

  auto STAGE = [&](int buf, int k0){
    #pragma unroll
    for (int half=0; half<2; ++half){
      int rb = half*64 + wave*16;
      size_t gArow = (size_t)(m0 + rb + rS)*lda + k0 + cS;
      size_t gBrow = (size_t)(n0 + rb + rS)*K + k0 + cS;
      gl_lds16(A  + gArow, &sA[buf][rb*32]);
      gl_lds16(Bt + gBrow, &sB[buf][rb*32]);
    }
  };

  STAGE(0, 0);
  __syncthreads();
  int nsteps = K >> 5;
  for (int t=0; t<nsteps; ++t){
    int cur = t & 1;
    if (t+1 < nsteps) STAGE(cur^1, (t+1)*32);
    short8 af[4], bfr[4];
    #pragma unroll
    for (int m=0;m<4;m++) af[m]  = *(const short8*)(&sA[cur][(wr + m*16 + row)*32 + kq]);
    #pragma unroll
    for (int n=0;n<4;n++) bfr[n] = *(const short8*)(&sB[cur][(wc + n*16 + row)*32 + kq]);
    #pragma unroll
    for (int m=0;m<4;m++)
      #pragma unroll
      for (int n=0;n<4;n++)
        acc[m][n] = __builtin_amdgcn_mfma_f32_16x16x32_bf16(af[m], bfr[n], acc[m][n], 0, 0, 0);
    __syncthreads();
  }
  #pragma unroll
  for (int m=0;m<4;m++)
    #pragma unroll
    for (int n=0;n<4;n++)
      #pragma unroll
      for (int r=0;r<4;r++){
        int rr = m0 + wr + m*16 + (lane>>4)*4 + r;
        int cc = n0 + wc + n*16 + (lane&15);
        C[(size_t)rr*N + cc] = acc[m][n][r];
      }
}

// ---- inclusive cumsum over t in DOUBLE: Gd[bh][t]; 3-phase scan (thread-local 32 + block scan) ----
__global__ __launch_bounds__(256) void k_cumsum(const float* __restrict__ Gc, double* __restrict__ Gd){
  int bh = blockIdx.x, tid = threadIdx.x;
  int lane = tid & 63, w = tid >> 6;
  const float* g = Gc + (size_t)bh*NT;
  double* out = Gd + (size_t)bh*NT;
  double tot = 0.0;
  #pragma unroll
  for (int i=0;i<32;i++) tot += (double)g[tid*32 + i];
  double v = tot;
  #pragma unroll
  for (int off=1; off<64; off<<=1){
    double y = shfl_up_dbl(v, off);
    if (lane >= off) v += y;
  }
  __shared__ double wsum[4];
  if (lane == 63) wsum[w] = v;
  __syncthreads();
  double add = 0.0;
  for (int w2=0; w2<w; ++w2) add += wsum[w2];
  double run = (v - tot) + add;      // exclusive prefix for this thread
  #pragma unroll
  for (int i=0;i<32;i++){
    run += (double)g[tid*32 + i];
    out[tid*32 + i] = run;
  }
}

// ---- phase A (MFMA, per-chunk): S_loc^T[n][k] = sum_j exp(Gend-Gj) v_j k_j, bf16 out ----
__global__ __launch_bounds__(256, 2) void k_phaseA(const unsigned short* __restrict__ qkb,
                                                   const unsigned short* __restrict__ vgb,
                                                   const double* __restrict__ Gd,
                                                   unsigned short* __restrict__ Sbc){
  __shared__ unsigned short vT[16384];   // [256 n][64 j] swizzled
  __shared__ unsigned short wkT[8192];   // [128 k][64 j] swizzled
  int blk = blockIdx.x, bh = blockIdx.y;
  int bb = bh>>2, hh = bh&3;
  int cs = blk*CHK, tid = threadIdx.x;
  int lane = tid & 63, w = tid >> 6;
  const double* Gb = Gd + (size_t)bh*NT;
  double Gend = Gb[cs + 63];
  #pragma unroll
  for (int it=0; it<8; ++it){
    int task = it*256 + tid;
    int j = task & 63, ng = task >> 6;
    short8 vv = *(const short8*)(vgb + (size_t)(bb*NT + cs + j)*VGS + hh*NHV + ng*8);
    #pragma unroll
    for (int e=0;e<8;e++)
      *(unsigned short*)lds_at(vT, ng*8+e, j, 128) = (unsigned short)vv[e];
  }
  #pragma unroll
  for (int it=0; it<4; ++it){
    int task = it*256 + tid;
    int j = task & 63, kg = task >> 6;
    float wj = expf((float)(Gend - Gb[cs + j]));
    short8 kv = *(const short8*)(qkb + (size_t)(bb*NT + cs + j)*QKS + 512 + hh*NHK + kg*8);
    #pragma unroll
    for (int e=0;e<8;e++)
      *(unsigned short*)lds_at(wkT, kg*8+e, j, 128) = f2bf(wj * bf2f((unsigned short)kv[e]));
  }
  __syncthreads();
  f32x4 sa[32];
  #pragma unroll
  for (int i=0;i<32;i++) sa[i] = (f32x4){0.f,0.f,0.f,0.f};
  short8 wa[2][2];
  #pragma unroll
  for (int mt=0;mt<2;mt++)
    #pragma unroll
    for (int kk=0;kk<2;kk++)
      wa[mt][kk] = *(short8*)lds_at(wkT, 32*w + mt*16 + (lane&15), kk*32 + (lane>>4)*8, 128);
  #pragma unroll
  for (int mt=0;mt<2;mt++)
    #pragma unroll
    for (int nt=0;nt<16;nt++)
      #pragma unroll
      for (int kk=0;kk<2;kk++){
        short8 b = *(short8*)lds_at(vT, nt*16 + (lane&15), kk*32 + (lane>>4)*8, 128);
        sa[mt*16+nt] = __builtin_amdgcn_mfma_f32_16x16x32_bf16(wa[mt][kk], b, sa[mt*16+nt], 0,0,0);
      }
  unsigned short* dst = Sbc + (size_t)(bh*NCHK + blk)*32768;
  #pragma unroll
  for (int mt=0;mt<2;mt++)
    #pragma unroll
    for (int nt=0;nt<16;nt++){
      int k = 32*w + mt*16 + (lane>>4)*4;
      int n = nt*16 + (lane&15);
      s16x4 p;
      #pragma unroll
      for (int r=0;r<4;r++) p[r] = (short)f2bf(sa[mt*16+nt][r]);
      *(s16x4*)(dst + (size_t)n*128 + k) = p;
    }
}

// ---------------- phase B: parallel elementwise scan, 4-deep prefetch ----------------
__global__ __launch_bounds__(256) void k_phaseB(unsigned short* __restrict__ Sbc,
                                                const double* __restrict__ Gd){
  int slice = blockIdx.x, bh = blockIdx.y;
  int tid = threadIdx.x;
  const double* Gb = Gd + (size_t)bh*NT;
  unsigned short* base = Sbc + (size_t)(bh*NCHK)*32768 + slice*1024 + tid*4;
  s16x4 c0 = *(const s16x4*)(base);
  f32x4 run;
  #pragma unroll
  for (int e=0;e<4;e++) run[e] = bf2f((unsigned short)c0[e]);
  s16x4 n0 = *(const s16x4*)(base + (size_t)1*32768);
  s16x4 n1 = *(const s16x4*)(base + (size_t)2*32768);
  s16x4 n2 = *(const s16x4*)(base + (size_t)3*32768);
  s16x4 n3 = *(const s16x4*)(base + (size_t)4*32768);
#define PB_STEP(U, BB) \
  { float resc = expf((float)(Gb[(BB)*CHK + 63] - Gb[(BB)*CHK - 1])); \
    s16x4 o_; \
    _Pragma("unroll") \
    for (int e=0;e<4;e++){ run[e] = resc*run[e] + bf2f((unsigned short)U[e]); o_[e] = (short)f2bf(run[e]); } \
    *(s16x4*)(base + (size_t)(BB)*32768) = o_; }
  for (int b=1; b<NCHK; b+=4){
    s16x4 u0=n0, u1=n1, u2=n2, u3=n3;
    if (b+4 < NCHK) n0 = *(const s16x4*)(base + (size_t)(b+4)*32768);
    if (b+5 < NCHK) n1 = *(const s16x4*)(base + (size_t)(b+5)*32768);
    if (b+6 < NCHK) n2 = *(const s16x4*)(base + (size_t)(b+6)*32768);
    if (b+7 < NCHK) n3 = *(const s16x4*)(base + (size_t)(b+7)*32768);
    PB_STEP(u0, b)
    if (b+1 < NCHK) PB_STEP(u1, b+1)
    if (b+2 < NCHK) PB_STEP(u2, b+2)
    if (b+3 < NCHK) PB_STEP(u3, b+3)
  }
#undef PB_STEP
}

// ---- phase C: o_inter hoisted pre-barrier; gate uses precomputed swish(g) ----
__global__ __launch_bounds__(256, 3) void k_phaseC(const unsigned short* __restrict__ qkb,
                                                   unsigned short* __restrict__ vgb,   // v cols 0-1023, swish(g) cols 1024+
                                                   const float* __restrict__ rmsw,
                                                   const double* __restrict__ Gd,
                                                   const unsigned short* __restrict__ Sbc){
  __shared__ unsigned short vT[16384];   // [256 n][64 j] swz; reused as o-tile [64][256]
  __shared__ unsigned short scp[4096];   // [64][64] swz
  __shared__ float Gsf[64];
  __shared__ float sI[64];               // SCALE*exp(Gsf)
  __shared__ float rsum[64][4];
  __shared__ float frl[64];
  __shared__ float rms_s[256];
  int blk = blockIdx.x, bh = blockIdx.y;
  int bb = bh>>2, hh = bh&3;
  int cs = blk*CHK, tid = threadIdx.x;
  int lane = tid&63, w = tid>>6;
  const double* Gb = Gd + (size_t)bh*NT;
  // tables
  rms_s[tid] = rmsw[tid];
  if (tid < 64){
    double ref = (cs == 0) ? 0.0 : Gb[cs-1];
    float g = (float)(Gb[cs+tid] - ref);
    Gsf[tid] = g;
    sI[tid] = SCALE * expf(g);
  }
  // stage vT (reg-staged transpose scatter)
  #pragma unroll
  for (int it=0; it<8; ++it){
    int task = it*256 + tid;
    int j = task & 63, ng = task >> 6;
    short8 vv = *(const short8*)(vgb + (size_t)(bb*NT + cs + j)*VGS + hh*NHV + ng*8);
    #pragma unroll
    for (int e=0;e<8;e++)
      *(unsigned short*)lds_at(vT, ng*8+e, j, 128) = (unsigned short)vv[e];
  }
  // o_inter BEFORE the barrier (no LDS deps): q,S from global, overlaps vT staging
  f32x4 oa[16];   // [rg*4 + nt]
  #pragma unroll
  for (int i=0;i<16;i++) oa[i] = (f32x4){0.f,0.f,0.f,0.f};
  if (blk > 0){
    const unsigned short* Sst = Sbc + (size_t)(bh*NCHK + blk - 1)*32768;
    #pragma unroll
    for (int kk=0;kk<4;kk++){
      short8 qrg[4];
      #pragma unroll
      for (int rg=0;rg<4;rg++)
        qrg[rg] = *(const short8*)(qkb + (size_t)(bb*NT + cs + rg*16 + (lane&15))*QKS
                                   + hh*NHK + kk*32 + (lane>>4)*8);
      #pragma unroll
      for (int nt=0;nt<4;nt++){
        short8 b = *(const short8*)(Sst + (size_t)(w*64 + nt*16 + (lane&15))*128
                                    + kk*32 + (lane>>4)*8);
        #pragma unroll
        for (int rg=0;rg<4;rg++)
          oa[rg*4+nt] = __builtin_amdgcn_mfma_f32_16x16x32_bf16(qrg[rg], b, oa[rg*4+nt], 0,0,0);
      }
    }
  }
  __syncthreads();   // vT + Gsf/sI/rms_s visible
  if (blk > 0){
    #pragma unroll
    for (int rg=0;rg<4;rg++)
      #pragma unroll
      for (int r=0;r<4;r++){
        float srow = sI[rg*16 + (lane>>4)*4 + r];
        #pragma unroll
        for (int nt=0;nt<4;nt++) oa[rg*4+nt][r] *= srow;
      }
  }
  // P for own row-group
  f32x4 pa[4];
  #pragma unroll
  for (int jt=0;jt<4;jt++) pa[jt] = (f32x4){0.f,0.f,0.f,0.f};
  {
    short8 qown[4];
    #pragma unroll
    for (int kk=0;kk<4;kk++)
      qown[kk] = *(const short8*)(qkb + (size_t)(bb*NT + cs + 16*w + (lane&15))*QKS
                                  + hh*NHK + kk*32 + (lane>>4)*8);
    #pragma unroll
    for (int jt=0;jt<4;jt++)
      #pragma unroll
      for (int kk=0;kk<4;kk++){
        short8 b = *(const short8*)(qkb + (size_t)(bb*NT + cs + jt*16 + (lane&15))*QKS
                                    + 512 + hh*NHK + kk*32 + (lane>>4)*8);
        pa[jt] = __builtin_amdgcn_mfma_f32_16x16x32_bf16(qown[kk], b, pa[jt], 0,0,0);
      }
  }
  // weight + causal mask -> scp (bf16)
  #pragma unroll
  for (int jt=0;jt<4;jt++)
    #pragma unroll
    for (int r=0;r<4;r++){
      int il = 16*w + (lane>>4)*4 + r;
      int jl = jt*16 + (lane&15);
      float wgt = (jl <= il) ? SCALE * expf(Gsf[il] - Gsf[jl]) : 0.f;
      *(unsigned short*)lds_at(scp, il, jl, 128) = f2bf(wgt * pa[jt][r]);
    }
  __syncthreads();   // scp written by all waves
  // PV: A = scp rows (all 4 row-groups), B = vT n-slice
  short8 af[4][2];
  #pragma unroll
  for (int rg=0;rg<4;rg++)
    #pragma unroll
    for (int kk=0;kk<2;kk++)
      af[rg][kk] = *(short8*)lds_at(scp, rg*16 + (lane&15), kk*32 + (lane>>4)*8, 128);
  #pragma unroll
  for (int nt=0;nt<4;nt++){
    short8 b0 = *(short8*)lds_at(vT, w*64 + nt*16 + (lane&15), 0*32 + (lane>>4)*8, 128);
    short8 b1 = *(short8*)lds_at(vT, w*64 + nt*16 + (lane&15), 1*32 + (lane>>4)*8, 128);
    #pragma unroll
    for (int rg=0;rg<4;rg++){
      oa[rg*4+nt] = __builtin_amdgcn_mfma_f32_16x16x32_bf16(af[rg][0], b0, oa[rg*4+nt], 0,0,0);
      oa[rg*4+nt] = __builtin_amdgcn_mfma_f32_16x16x32_bf16(af[rg][1], b1, oa[rg*4+nt], 0,0,0);
    }
  }
  // RMS partials over this wave's 64 cols, then cross-wave reduce
  float pp[16];
  #pragma unroll
  for (int rg=0;rg<4;rg++)
    #pragma unroll
    for (int r=0;r<4;r++){
      float s = 0.f;
      #pragma unroll
      for (int nt=0;nt<4;nt++) s += oa[rg*4+nt][r]*oa[rg*4+nt][r];
      pp[rg*4+r] = s;
    }
  #pragma unroll
  for (int i=0;i<16;i++){
    #pragma unroll
    for (int off=1; off<16; off<<=1) pp[i] += __shfl_xor(pp[i], off, 16);
  }
  if ((lane&15) == 0){
    int l4 = lane>>4;
    #pragma unroll
    for (int rg=0;rg<4;rg++)
      #pragma unroll
      for (int r=0;r<4;r++)
        rsum[rg*16 + l4*4 + r][w] = pp[rg*4+r];
  }
  __syncthreads();   // also: all waves done reading vT (PV complete)
  if (tid < 64)
    frl[tid] = rsqrtf((rsum[tid][0]+rsum[tid][1]+rsum[tid][2]+rsum[tid][3])*(1.f/256.f) + 1e-5f);
  __syncthreads();
  // write normalized o into oLDS (vT reused)
  char* oLDS = (char*)vT;
  float fv[4][4];
  #pragma unroll
  for (int rg=0;rg<4;rg++)
    #pragma unroll
    for (int r=0;r<4;r++) fv[rg][r] = frl[rg*16 + (lane>>4)*4 + r];
  #pragma unroll
  for (int nt=0;nt<4;nt++){
    int n = w*64 + nt*16 + (lane&15);
    float rw = rms_s[n];
    #pragma unroll
    for (int rg=0;rg<4;rg++)
      #pragma unroll
      for (int r=0;r<4;r++){
        int rowl = rg*16 + (lane>>4)*4 + r;
        *(unsigned short*)(oLDS + osw(rowl, n*2)) = f2bf(oa[rg*4+nt][r] * fv[rg][r] * rw);
      }
  }
  __syncthreads();
  // coalesced gate pass: o2 = o_n * swish_g (precomputed), in-place over g half
  #pragma unroll
  for (int it=0; it<8; ++it){
    int task = it*256 + tid;
    int rowl = task >> 5, c8 = (task & 31)*8;
    size_t gbase = (size_t)(bb*NT + cs + rowl)*VGS + 1024 + hh*NHV + c8;
    short8 g8 = *(const short8*)(vgb + gbase);
    short8 o8 = *(const short8*)(oLDS + osw(rowl, c8*2));
    short8 out;
    #pragma unroll
    for (int e=0;e<8;e++)
      out[e] = (short)f2bf(bf2f((unsigned short)o8[e]) * bf2f((unsigned short)g8[e]));
    *(short8*)(vgb + gbase) = out;
  }
}

// ---------------- launch ----------------
extern "C" void kernel_launch(void* const* d_in, const int* in_sizes, int n_in,
                              void* d_out, int out_size, void* d_ws, size_t ws_size,
                              hipStream_t stream) {
  (void)in_sizes; (void)n_in; (void)out_size;
  const float* hs  = (const float*)d_in[0];
  const float* Wq  = (const float*)d_in[1];
  const float* Wk  = (const float*)d_in[2];
  const float* Wv  = (const float*)d_in[3];
  const float* Wa  = (const float*)d_in[4];
  const float* Wg  = (const float*)d_in[5];
  const float* Wo  = (const float*)d_in[6];
  const float* Al  = (const float*)d_in[7];
  const float* dtb = (const float*)d_in[8];
  const float* rmsw= (const float*)d_in[9];
  char* ws = (char*)d_ws;

  // workspace layout — total stays within known-safe 176,947,200 B
  constexpr size_t MB = 1048576;
  constexpr size_t OFF_QK   = 0;            // 32MB bf16 merged q|k  [16384][1024]
  constexpr size_t OFF_VG   = 32*MB;        // 64MB bf16 merged v|swish(g) [16384][2048]
  constexpr size_t OFF_WQKH = 96*MB;        // 2MB concat [wq^T; wk^T] hi
  constexpr size_t OFF_WQKL = 98*MB;        // 2MB concat [wq^T; wk^T] lo
  constexpr size_t OFF_WVG  = 100*MB;       // 4MB concat [wv^T; wg^T]
  constexpr size_t OFF_WO   = 104*MB;       // 2MB
  constexpr size_t OFF_GC   = 106*MB;                 // 256KB
  constexpr size_t OFF_GD   = 106*MB + 262144;        // 512KB
  constexpr size_t OFF_SBC  = 107*MB;       // 64MB bf16 chunk states; hsh aliases pre-phaseA
  constexpr size_t WS_REQUIRED = 176947200;
  if (ws_size < WS_REQUIRED) return;

  unsigned short* qkb  = (unsigned short*)(ws + OFF_QK);
  unsigned short* vgb  = (unsigned short*)(ws + OFF_VG);
  unsigned short* wqkh = (unsigned short*)(ws + OFF_WQKH);
  unsigned short* wqkl = (unsigned short*)(ws + OFF_WQKL);
  unsigned short* wvgt = (unsigned short*)(ws + OFF_WVG);
  unsigned short* wot  = (unsigned short*)(ws + OFF_WO);
  float* Gc   = (float*)(ws + OFF_GC);
  double* Gd  = (double*)(ws + OFF_GD);
  unsigned short* Sbc = (unsigned short*)(ws + OFF_SBC);
  unsigned short* hsh = (unsigned short*)(ws + OFF_SBC);          // 32MB, dead before phaseA

  // fused prep: alphacast (blocks 0..16383) + LDS-tiled weight transposes (16384..17407)
  k_prep<<<17408, 256, 0, stream>>>(hs, Wa, Al, dtb, Gc, hsh,
                                    Wq, Wk, Wv, Wg, Wo, wqkh, wqkl, wvgt, wot);

  // projections: merged q|k 2-pass (B hi+lo); merged v|g single-pass with swish on g half
  k_gemm2<1,0><<<dim3(128,8), 256, 0, stream>>>(hsh, wqkh, wqkl, qkb, 16384, 1024, 1024);
  k_gemm2<0,2><<<dim3(128,16), 256, 0, stream>>>(hsh, wvgt, nullptr, vgb, 16384, 2048, 1024);

  k_cumsum<<<8, 256, 0, stream>>>(Gc, Gd);

  k_phaseA<<<dim3(NCHK,8), 256, 0, stream>>>(qkb, vgb, Gd, Sbc);
  k_phaseB<<<dim3(32,8), 256, 0, stream>>>(Sbc, Gd);
  k_phaseC<<<dim3(NCHK,8), 256, 0, stream>>>(qkb, vgb, rmsw, Gd, Sbc);

  // final GEMM: o2 (= g half of vgb, lda 2048) @ Wo^T
  k_gemm<<<dim3(128,8), 256, 0, stream>>>(vgb + 1024, wot, (float*)d_out, 16384, 1024, 1024, VGS);
}

// Round 28
// 391.115 us; speedup vs baseline: 1.0073x; 1.0073x over previous
//
#include <hip/hip_runtime.h>
#include <cstdint>
#include <cstddef>

// Problem constants
#define NB 2
#define NT 8192
#define ND 1024
#define NH 4
#define NV 1024
#define NHV 256
#define NHK 128
#define CHK 64
#define NCHK 128            // chunks per (b,h)
#define QKS 1024            // merged q|k row stride
#define VGS 2048            // merged v|g row stride
#define SCALE 0.08838834764831845f   // HK^-0.5

using f32x4 = __attribute__((ext_vector_type(4))) float;
using short8 = __attribute__((ext_vector_type(8))) short;
using s16x4 = __attribute__((ext_vector_type(4))) short;

__device__ __forceinline__ float bf2f(unsigned short u){
  union { unsigned int i; float f; } t; t.i = ((unsigned int)u) << 16; return t.f;
}
__device__ __forceinline__ unsigned short f2bf(float f){
  union { float f; unsigned int i; } t; t.f = f;
  unsigned int r = t.i + 0x7fffu + ((t.i >> 16) & 1u);
  return (unsigned short)(r >> 16);
}
__device__ __forceinline__ double shfl_up_dbl(double v, int off){
  union { double d; unsigned int u[2]; } a, r;
  a.d = v;
  r.u[0] = __shfl_up(a.u[0], off, 64);
  r.u[1] = __shfl_up(a.u[1], off, 64);
  return r.d;
}
// Swizzled LDS accessor for bf16 tiles: row-major, rowBytes in {128,256}.
__device__ __forceinline__ void* lds_at(void* base, int row, int colElem, int rowBytes){
  return (void*)((char*)base + row*rowBytes + (((colElem*2) ^ ((row&7)<<4))));
}
// swizzle for the [64][256] bf16 o-tile (512B rows)
__device__ __forceinline__ int osw(int rowl, int byteoff){
  return rowl*512 + (byteoff ^ (((rowl>>2)&7)<<4));
}
// XCD-chunked, A-panel-major block swizzle. total = gx*gy must be %8==0.
__device__ __forceinline__ void xcd_swizzle(int gx, int gy, int& bx, int& by){
  int flat = blockIdx.y*gx + blockIdx.x;
  int total = gx*gy;
  int wg = (flat & 7)*(total >> 3) + (flat >> 3);
  bx = wg / gy;
  by = wg % gy;
}

// ---- async global->LDS, 16B per lane; dest is wave-uniform base + lane*16 (m97 pattern) ----
typedef const __attribute__((address_space(1))) unsigned int as1_u32;
typedef __attribute__((address_space(3))) unsigned int as3_u32;
__device__ __forceinline__ void gl_lds16(const void* g_lane, void* lds_uniform){
  __builtin_amdgcn_global_load_lds((as1_u32*)(uintptr_t)g_lane,
                                   (as3_u32*)(unsigned int)(uintptr_t)lds_uniform,
                                   16, 0, 0);
}

// ---- fused prep: blocks 0..16383 = alphacast; 16384..17407 = LDS-tiled weight transposes ----
__global__ __launch_bounds__(256) void k_prep(const float* __restrict__ hs,
                                              const float* __restrict__ Wa,
                                              const float* __restrict__ Al,
                                              const float* __restrict__ dtb,
                                              float* __restrict__ Gc,
                                              unsigned short* __restrict__ hsh,
                                              const float* __restrict__ Wq,
                                              const float* __restrict__ Wk,
                                              const float* __restrict__ Wv,
                                              const float* __restrict__ Wg,
                                              const float* __restrict__ Wo,
                                              unsigned short* __restrict__ wqkh,
                                              unsigned short* __restrict__ wqkl,
                                              unsigned short* __restrict__ wvgt,
                                              unsigned short* __restrict__ wot){
  int b = blockIdx.x, tid = threadIdx.x;
  if (b < 16384){
    // ---- alphacast: cast hs row to bf16 + alpha = hs@Wa -> gk (pre-cumsum, exact fp32) ----
    int rowi = b;
    const float* h = hs + (size_t)rowi*ND;
    f32x4 x = *(const f32x4*)(h + tid*4);
    s16x4 hb;
    #pragma unroll
    for (int e=0;e<4;e++) hb[e] = (short)f2bf(x[e]);
    *(s16x4*)(hsh + (size_t)rowi*ND + tid*4) = hb;
    float a0=0.f,a1=0.f,a2=0.f,a3=0.f;
    #pragma unroll
    for (int e=0;e<4;e++){
      int d = tid*4+e;
      a0 += x[e]*Wa[d*4+0]; a1 += x[e]*Wa[d*4+1]; a2 += x[e]*Wa[d*4+2]; a3 += x[e]*Wa[d*4+3];
    }
    #pragma unroll
    for (int off=32; off>0; off>>=1){
      a0 += __shfl_down(a0, off, 64); a1 += __shfl_down(a1, off, 64);
      a2 += __shfl_down(a2, off, 64); a3 += __shfl_down(a3, off, 64);
    }
    __shared__ float red[4][4];
    if ((tid&63)==0){ int w = tid>>6; red[w][0]=a0; red[w][1]=a1; red[w][2]=a2; red[w][3]=a3; }
    __syncthreads();
    if (tid < 4){
      float al = red[0][tid]+red[1][tid]+red[2][tid]+red[3][tid];
      float xx = al + dtb[tid];
      float sp = (xx > 20.f) ? xx : log1pf(expf(xx));
      float gkv = -expf(Al[tid]) * sp;
      int bb = rowi >> 13, t = rowi & (NT-1);
      Gc[((size_t)(bb*NH + tid))*NT + t] = gkv;
    }
  } else {
    // ---- LDS-tiled 64x64 transpose: coalesced reads AND writes ----
    __shared__ float tile[64][65];
    int b2 = b - 16384;
    const float* src; int C; int rt, ct; int hilo = 0; size_t boff = 0;
    unsigned short *dsth = nullptr, *dstl = nullptr;
    if (b2 < 128){          src = Wq; C = 512;  rt = b2 >> 3;          ct = b2 & 7;  hilo = 1; boff = 0;          dsth = wqkh; dstl = wqkl; }
    else if (b2 < 256){     src = Wk; C = 512;  rt = (b2-128) >> 3;    ct = (b2-128) & 7;  hilo = 1; boff = 512*1024;  dsth = wqkh; dstl = wqkl; }
    else if (b2 < 512){     src = Wv; C = 1024; rt = (b2-256) >> 4;    ct = (b2-256) & 15; boff = 0;          dsth = wvgt; }
    else if (b2 < 768){     src = Wg; C = 1024; rt = (b2-512) >> 4;    ct = (b2-512) & 15; boff = 1024*1024; dsth = wvgt; }
    else {                  src = Wo; C = 1024; rt = (b2-768) >> 4;    ct = (b2-768) & 15; boff = 0;          dsth = wot;  }
    int r0 = rt*64, c0 = ct*64;
    #pragma unroll
    for (int it=0; it<16; ++it){
      int r = it*4 + (tid>>6);
      int c = tid & 63;
      tile[r][c] = src[(size_t)(r0+r)*C + c0 + c];
    }
    __syncthreads();
    #pragma unroll
    for (int it=0; it<16; ++it){
      int c = it*4 + (tid>>6);
      int r = tid & 63;
      float x = tile[r][c];
      unsigned short h = f2bf(x);
      dsth[boff + (size_t)(c0+c)*1024 + r0 + r] = h;
      if (hilo) dstl[boff + (size_t)(c0+c)*1024 + r0 + r] = f2bf(x - bf2f(h));
    }
  }
}

// --- 2-phase dbuf GEMM: C = A@Bth^T (+A@Btl^T if BSPLIT) ---
// GSWISH: 0 = none; 2 = swish where n0 >= 1024 (merged v|g output).
template<int BSPLIT, int GSWISH>
__global__ __launch_bounds__(256, BSPLIT ? 3 : 4)
void k_gemm2(const unsigned short* __restrict__ A2h,
             const unsigned short* __restrict__ Bth,
             const unsigned short* __restrict__ Btl,
             unsigned short* __restrict__ C, int M, int N, int K){
  __shared__ unsigned short sA[2][4096];
  __shared__ unsigned short sB[2][4096];
  __shared__ unsigned short sBl[BSPLIT ? 2*4096 : 8];
  int tid = threadIdx.x, lane = tid & 63, wave = tid >> 6;
  int bx, by;
  xcd_swizzle(gridDim.x, gridDim.y, bx, by);
  int m0 = bx*128, n0 = by*128;
  int wr = (wave>>1)*64, wc = (wave&1)*64;
  int row = lane & 15, kq = (lane>>4)*8;
  int rS = lane>>2, cS = (lane&3)*8;
  f32x4 acc[4][4];
  #pragma unroll
  for (int m=0;m<4;m++)
    #pragma unroll
    for (int n=0;n<4;n++)
      #pragma unroll
      for (int r=0;r<4;r++) acc[m][n][r] = 0.f;

  auto STAGE = [&](int buf, int k0){
    #pragma unroll
    for (int half=0; half<2; ++half){
      int rb = half*64 + wave*16;
      size_t gArow = (size_t)(m0 + rb + rS)*K + k0 + cS;
      size_t gBrow = (size_t)(n0 + rb + rS)*K + k0 + cS;
      gl_lds16(A2h + gArow, &sA[buf][rb*32]);
      gl_lds16(Bth + gBrow, &sB[buf][rb*32]);
      if (BSPLIT) gl_lds16(Btl + gBrow, &sBl[buf*4096 + rb*32]);
    }
  };

  STAGE(0, 0);
  __syncthreads();
  int nsteps = K >> 5;
  for (int t=0; t<nsteps; ++t){
    int cur = t & 1;
    if (t+1 < nsteps) STAGE(cur^1, (t+1)*32);
    short8 ah[4], bh[4];
    #pragma unroll
    for (int m=0;m<4;m++) ah[m] = *(const short8*)(&sA[cur][(wr + m*16 + row)*32 + kq]);
    #pragma unroll
    for (int n=0;n<4;n++) bh[n] = *(const short8*)(&sB[cur][(wc + n*16 + row)*32 + kq]);
    #pragma unroll
    for (int m=0;m<4;m++)
      #pragma unroll
      for (int n=0;n<4;n++)
        acc[m][n] = __builtin_amdgcn_mfma_f32_16x16x32_bf16(ah[m], bh[n], acc[m][n], 0, 0, 0);
    if (BSPLIT){
      short8 bl[4];
      #pragma unroll
      for (int n=0;n<4;n++) bl[n] = *(const short8*)(&sBl[cur*4096 + (wc + n*16 + row)*32 + kq]);
      #pragma unroll
      for (int m=0;m<4;m++)
        #pragma unroll
        for (int n=0;n<4;n++)
          acc[m][n] = __builtin_amdgcn_mfma_f32_16x16x32_bf16(ah[m], bl[n], acc[m][n], 0, 0, 0);
    }
    __syncthreads();
  }
  bool dosw = (GSWISH == 2) && (n0 >= 1024);
  #pragma unroll
  for (int m=0;m<4;m++)
    #pragma unroll
    for (int n=0;n<4;n++)
      #pragma unroll
      for (int r=0;r<4;r++){
        int rr = m0 + wr + m*16 + (lane>>4)*4 + r;
        int cc = n0 + wc + n*16 + (lane&15);
        float v = acc[m][n][r];
        if (dosw) v = v / (1.f + expf(-v));
        C[(size_t)rr*N + cc] = f2bf(v);
      }
}

// ---------------- final GEMM (fp32 out), dbuf prefetch, strided A ----------------
__global__ __launch_bounds__(256, 4) void k_gemm(const unsigned short* __restrict__ A,
                                                 const unsigned short* __restrict__ Bt,
                                                 float* __restrict__ C, int M, int N, int K,
                                                 int lda){
  __shared__ unsigned short sA[2][4096];
  __shared__ unsigned short sB[2][4096];
  int tid = threadIdx.x, lane = tid & 63, wave = tid >> 6;
  int bx, by;
  xcd_swizzle(gridDim.x, gridDim.y, bx, by);
  int m0 = bx*128, n0 = by*128;
  int wr = (wave>>1)*64, wc = (wave&1)*64;
  int row = lane & 15, kq = (lane>>4)*8;
  int rS = lane>>2, cS = (lane&3)*8;
  f32x4 acc[4][4];
  #pragma unroll
  for (int m=0;m<4;m++)
    #pragma unroll
    for (int n=0;n<4;n++)
      #pragma unroll
      for (int r=0;r<4;r++) acc[m][n][r] = 0.f;

  auto STAGE = [&](int buf, int k0){
    #pragma unroll
    for (int half=0; half<2; ++half){
      int rb = half*64 + wave*16;
      size_t gArow = (size_t)(m0 + rb + rS)*lda + k0 + cS;
      size_t gBrow = (size_t)(n0 + rb + rS)*K + k0 + cS;
      gl_lds16(A  + gArow, &sA[buf][rb*32]);
      gl_lds16(Bt + gBrow, &sB[buf][rb*32]);
    }
  };

  STAGE(0, 0);
  __syncthreads();
  int nsteps = K >> 5;
  for (int t=0; t<nsteps; ++t){
    int cur = t & 1;
    if (t+1 < nsteps) STAGE(cur^1, (t+1)*32);
    short8 af[4], bfr[4];
    #pragma unroll
    for (int m=0;m<4;m++) af[m]  = *(const short8*)(&sA[cur][(wr + m*16 + row)*32 + kq]);
    #pragma unroll
    for (int n=0;n<4;n++) bfr[n] = *(const short8*)(&sB[cur][(wc + n*16 + row)*32 + kq]);
    #pragma unroll
    for (int m=0;m<4;m++)
      #pragma unroll
      for (int n=0;n<4;n++)
        acc[m][n] = __builtin_amdgcn_mfma_f32_16x16x32_bf16(af[m], bfr[n], acc[m][n], 0, 0, 0);
    __syncthreads();
  }
  #pragma unroll
  for (int m=0;m<4;m++)
    #pragma unroll
    for (int n=0;n<4;n++)
      #pragma unroll
      for (int r=0;r<4;r++){
        int rr = m0 + wr + m*16 + (lane>>4)*4 + r;
        int cc = n0 + wc + n*16 + (lane&15);
        C[(size_t)rr*N + cc] = acc[m][n][r];
      }
}

// ---- inclusive cumsum over t in DOUBLE: Gd[bh][t]; 3-phase scan (thread-local 32 + block scan) ----
__global__ __launch_bounds__(256) void k_cumsum(const float* __restrict__ Gc, double* __restrict__ Gd){
  int bh = blockIdx.x, tid = threadIdx.x;
  int lane = tid & 63, w = tid >> 6;
  const float* g = Gc + (size_t)bh*NT;
  double* out = Gd + (size_t)bh*NT;
  double tot = 0.0;
  #pragma unroll
  for (int i=0;i<32;i++) tot += (double)g[tid*32 + i];
  double v = tot;
  #pragma unroll
  for (int off=1; off<64; off<<=1){
    double y = shfl_up_dbl(v, off);
    if (lane >= off) v += y;
  }
  __shared__ double wsum[4];
  if (lane == 63) wsum[w] = v;
  __syncthreads();
  double add = 0.0;
  for (int w2=0; w2<w; ++w2) add += wsum[w2];
  double run = (v - tot) + add;      // exclusive prefix for this thread
  #pragma unroll
  for (int i=0;i<32;i++){
    run += (double)g[tid*32 + i];
    out[tid*32 + i] = run;
  }
}

// ---- phase A (MFMA, per-chunk, n-split z=2): S_loc^T[n][k] = sum_j exp(Gend-Gj) v_j k_j ----
// Each z-half stages 128 of the 256 v-columns (16KB) + full weighted-k (16KB): 32KB LDS,
// 64 acc VGPRs -> 3 blocks/CU (vs 2 at the unsplit 48KB/128-acc version).
__global__ __launch_bounds__(256, 3) void k_phaseA(const unsigned short* __restrict__ qkb,
                                                   const unsigned short* __restrict__ vgb,
                                                   const double* __restrict__ Gd,
                                                   unsigned short* __restrict__ Sbc){
  __shared__ unsigned short vT[8192];    // [128 n][64 j] swizzled (this z-half)
  __shared__ unsigned short wkT[8192];   // [128 k][64 j] swizzled
  int blk = blockIdx.x, bh = blockIdx.y, z = blockIdx.z;
  int bb = bh>>2, hh = bh&3;
  int cs = blk*CHK, tid = threadIdx.x;
  int lane = tid & 63, w = tid >> 6;
  const double* Gb = Gd + (size_t)bh*NT;
  double Gend = Gb[cs + 63];
  #pragma unroll
  for (int it=0; it<4; ++it){
    int task = it*256 + tid;
    int j = task & 63, ng = task >> 6;   // ng in 0..15
    short8 vv = *(const short8*)(vgb + (size_t)(bb*NT + cs + j)*VGS + hh*NHV + z*128 + ng*8);
    #pragma unroll
    for (int e=0;e<8;e++)
      *(unsigned short*)lds_at(vT, ng*8+e, j, 128) = (unsigned short)vv[e];
  }
  #pragma unroll
  for (int it=0; it<4; ++it){
    int task = it*256 + tid;
    int j = task & 63, kg = task >> 6;
    float wj = expf((float)(Gend - Gb[cs + j]));
    short8 kv = *(const short8*)(qkb + (size_t)(bb*NT + cs + j)*QKS + 512 + hh*NHK + kg*8);
    #pragma unroll
    for (int e=0;e<8;e++)
      *(unsigned short*)lds_at(wkT, kg*8+e, j, 128) = f2bf(wj * bf2f((unsigned short)kv[e]));
  }
  __syncthreads();
  f32x4 sa[16];
  #pragma unroll
  for (int i=0;i<16;i++) sa[i] = (f32x4){0.f,0.f,0.f,0.f};
  short8 wa[2][2];
  #pragma unroll
  for (int mt=0;mt<2;mt++)
    #pragma unroll
    for (int kk=0;kk<2;kk++)
      wa[mt][kk] = *(short8*)lds_at(wkT, 32*w + mt*16 + (lane&15), kk*32 + (lane>>4)*8, 128);
  #pragma unroll
  for (int mt=0;mt<2;mt++)
    #pragma unroll
    for (int nt=0;nt<8;nt++)
      #pragma unroll
      for (int kk=0;kk<2;kk++){
        short8 b = *(short8*)lds_at(vT, nt*16 + (lane&15), kk*32 + (lane>>4)*8, 128);
        sa[mt*8+nt] = __builtin_amdgcn_mfma_f32_16x16x32_bf16(wa[mt][kk], b, sa[mt*8+nt], 0,0,0);
      }
  unsigned short* dst = Sbc + (size_t)(bh*NCHK + blk)*32768 + (size_t)z*16384;
  #pragma unroll
  for (int mt=0;mt<2;mt++)
    #pragma unroll
    for (int nt=0;nt<8;nt++){
      int k = 32*w + mt*16 + (lane>>4)*4;
      int n = nt*16 + (lane&15);
      s16x4 p;
      #pragma unroll
      for (int r=0;r<4;r++) p[r] = (short)f2bf(sa[mt*8+nt][r]);
      *(s16x4*)(dst + (size_t)n*128 + k) = p;
    }
}

// ---------------- phase B: parallel elementwise scan, 4-deep prefetch ----------------
__global__ __launch_bounds__(256) void k_phaseB(unsigned short* __restrict__ Sbc,
                                                const double* __restrict__ Gd){
  int slice = blockIdx.x, bh = blockIdx.y;
  int tid = threadIdx.x;
  const double* Gb = Gd + (size_t)bh*NT;
  unsigned short* base = Sbc + (size_t)(bh*NCHK)*32768 + slice*1024 + tid*4;
  s16x4 c0 = *(const s16x4*)(base);
  f32x4 run;
  #pragma unroll
  for (int e=0;e<4;e++) run[e] = bf2f((unsigned short)c0[e]);
  s16x4 n0 = *(const s16x4*)(base + (size_t)1*32768);
  s16x4 n1 = *(const s16x4*)(base + (size_t)2*32768);
  s16x4 n2 = *(const s16x4*)(base + (size_t)3*32768);
  s16x4 n3 = *(const s16x4*)(base + (size_t)4*32768);
#define PB_STEP(U, BB) \
  { float resc = expf((float)(Gb[(BB)*CHK + 63] - Gb[(BB)*CHK - 1])); \
    s16x4 o_; \
    _Pragma("unroll") \
    for (int e=0;e<4;e++){ run[e] = resc*run[e] + bf2f((unsigned short)U[e]); o_[e] = (short)f2bf(run[e]); } \
    *(s16x4*)(base + (size_t)(BB)*32768) = o_; }
  for (int b=1; b<NCHK; b+=4){
    s16x4 u0=n0, u1=n1, u2=n2, u3=n3;
    if (b+4 < NCHK) n0 = *(const s16x4*)(base + (size_t)(b+4)*32768);
    if (b+5 < NCHK) n1 = *(const s16x4*)(base + (size_t)(b+5)*32768);
    if (b+6 < NCHK) n2 = *(const s16x4*)(base + (size_t)(b+6)*32768);
    if (b+7 < NCHK) n3 = *(const s16x4*)(base + (size_t)(b+7)*32768);
    PB_STEP(u0, b)
    if (b+1 < NCHK) PB_STEP(u1, b+1)
    if (b+2 < NCHK) PB_STEP(u2, b+2)
    if (b+3 < NCHK) PB_STEP(u3, b+3)
  }
#undef PB_STEP
}

// ---- phase C: o_inter hoisted pre-barrier; gate uses precomputed swish(g) ----
__global__ __launch_bounds__(256, 3) void k_phaseC(const unsigned short* __restrict__ qkb,
                                                   unsigned short* __restrict__ vgb,   // v cols 0-1023, swish(g) cols 1024+
                                                   const float* __restrict__ rmsw,
                                                   const double* __restrict__ Gd,
                                                   const unsigned short* __restrict__ Sbc){
  __shared__ unsigned short vT[16384];   // [256 n][64 j] swz; reused as o-tile [64][256]
  __shared__ unsigned short scp[4096];   // [64][64] swz
  __shared__ float Gsf[64];
  __shared__ float sI[64];               // SCALE*exp(Gsf)
  __shared__ float rsum[64][4];
  __shared__ float frl[64];
  __shared__ float rms_s[256];
  int blk = blockIdx.x, bh = blockIdx.y;
  int bb = bh>>2, hh = bh&3;
  int cs = blk*CHK, tid = threadIdx.x;
  int lane = tid&63, w = tid>>6;
  const double* Gb = Gd + (size_t)bh*NT;
  // tables
  rms_s[tid] = rmsw[tid];
  if (tid < 64){
    double ref = (cs == 0) ? 0.0 : Gb[cs-1];
    float g = (float)(Gb[cs+tid] - ref);
    Gsf[tid] = g;
    sI[tid] = SCALE * expf(g);
  }
  // stage vT (reg-staged transpose scatter)
  #pragma unroll
  for (int it=0; it<8; ++it){
    int task = it*256 + tid;
    int j = task & 63, ng = task >> 6;
    short8 vv = *(const short8*)(vgb + (size_t)(bb*NT + cs + j)*VGS + hh*NHV + ng*8);
    #pragma unroll
    for (int e=0;e<8;e++)
      *(unsigned short*)lds_at(vT, ng*8+e, j, 128) = (unsigned short)vv[e];
  }
  // o_inter BEFORE the barrier (no LDS deps): q,S from global, overlaps vT staging
  f32x4 oa[16];   // [rg*4 + nt]
  #pragma unroll
  for (int i=0;i<16;i++) oa[i] = (f32x4){0.f,0.f,0.f,0.f};
  if (blk > 0){
    const unsigned short* Sst = Sbc + (size_t)(bh*NCHK + blk - 1)*32768;
    #pragma unroll
    for (int kk=0;kk<4;kk++){
      short8 qrg[4];
      #pragma unroll
      for (int rg=0;rg<4;rg++)
        qrg[rg] = *(const short8*)(qkb + (size_t)(bb*NT + cs + rg*16 + (lane&15))*QKS
                                   + hh*NHK + kk*32 + (lane>>4)*8);
      #pragma unroll
      for (int nt=0;nt<4;nt++){
        short8 b = *(const short8*)(Sst + (size_t)(w*64 + nt*16 + (lane&15))*128
                                    + kk*32 + (lane>>4)*8);
        #pragma unroll
        for (int rg=0;rg<4;rg++)
          oa[rg*4+nt] = __builtin_amdgcn_mfma_f32_16x16x32_bf16(qrg[rg], b, oa[rg*4+nt], 0,0,0);
      }
    }
  }
  __syncthreads();   // vT + Gsf/sI/rms_s visible
  if (blk > 0){
    #pragma unroll
    for (int rg=0;rg<4;rg++)
      #pragma unroll
      for (int r=0;r<4;r++){
        float srow = sI[rg*16 + (lane>>4)*4 + r];
        #pragma unroll
        for (int nt=0;nt<4;nt++) oa[rg*4+nt][r] *= srow;
      }
  }
  // P for own row-group
  f32x4 pa[4];
  #pragma unroll
  for (int jt=0;jt<4;jt++) pa[jt] = (f32x4){0.f,0.f,0.f,0.f};
  {
    short8 qown[4];
    #pragma unroll
    for (int kk=0;kk<4;kk++)
      qown[kk] = *(const short8*)(qkb + (size_t)(bb*NT + cs + 16*w + (lane&15))*QKS
                                  + hh*NHK + kk*32 + (lane>>4)*8);
    #pragma unroll
    for (int jt=0;jt<4;jt++)
      #pragma unroll
      for (int kk=0;kk<4;kk++){
        short8 b = *(const short8*)(qkb + (size_t)(bb*NT + cs + jt*16 + (lane&15))*QKS
                                    + 512 + hh*NHK + kk*32 + (lane>>4)*8);
        pa[jt] = __builtin_amdgcn_mfma_f32_16x16x32_bf16(qown[kk], b, pa[jt], 0,0,0);
      }
  }
  // weight + causal mask -> scp (bf16)
  #pragma unroll
  for (int jt=0;jt<4;jt++)
    #pragma unroll
    for (int r=0;r<4;r++){
      int il = 16*w + (lane>>4)*4 + r;
      int jl = jt*16 + (lane&15);
      float wgt = (jl <= il) ? SCALE * expf(Gsf[il] - Gsf[jl]) : 0.f;
      *(unsigned short*)lds_at(scp, il, jl, 128) = f2bf(wgt * pa[jt][r]);
    }
  __syncthreads();   // scp written by all waves
  // PV: A = scp rows (all 4 row-groups), B = vT n-slice
  short8 af[4][2];
  #pragma unroll
  for (int rg=0;rg<4;rg++)
    #pragma unroll
    for (int kk=0;kk<2;kk++)
      af[rg][kk] = *(short8*)lds_at(scp, rg*16 + (lane&15), kk*32 + (lane>>4)*8, 128);
  #pragma unroll
  for (int nt=0;nt<4;nt++){
    short8 b0 = *(short8*)lds_at(vT, w*64 + nt*16 + (lane&15), 0*32 + (lane>>4)*8, 128);
    short8 b1 = *(short8*)lds_at(vT, w*64 + nt*16 + (lane&15), 1*32 + (lane>>4)*8, 128);
    #pragma unroll
    for (int rg=0;rg<4;rg++){
      oa[rg*4+nt] = __builtin_amdgcn_mfma_f32_16x16x32_bf16(af[rg][0], b0, oa[rg*4+nt], 0,0,0);
      oa[rg*4+nt] = __builtin_amdgcn_mfma_f32_16x16x32_bf16(af[rg][1], b1, oa[rg*4+nt], 0,0,0);
    }
  }
  // RMS partials over this wave's 64 cols, then cross-wave reduce
  float pp[16];
  #pragma unroll
  for (int rg=0;rg<4;rg++)
    #pragma unroll
    for (int r=0;r<4;r++){
      float s = 0.f;
      #pragma unroll
      for (int nt=0;nt<4;nt++) s += oa[rg*4+nt][r]*oa[rg*4+nt][r];
      pp[rg*4+r] = s;
    }
  #pragma unroll
  for (int i=0;i<16;i++){
    #pragma unroll
    for (int off=1; off<16; off<<=1) pp[i] += __shfl_xor(pp[i], off, 16);
  }
  if ((lane&15) == 0){
    int l4 = lane>>4;
    #pragma unroll
    for (int rg=0;rg<4;rg++)
      #pragma unroll
      for (int r=0;r<4;r++)
        rsum[rg*16 + l4*4 + r][w] = pp[rg*4+r];
  }
  __syncthreads();   // also: all waves done reading vT (PV complete)
  if (tid < 64)
    frl[tid] = rsqrtf((rsum[tid][0]+rsum[tid][1]+rsum[tid][2]+rsum[tid][3])*(1.f/256.f) + 1e-5f);
  __syncthreads();
  // write normalized o into oLDS (vT reused)
  char* oLDS = (char*)vT;
  float fv[4][4];
  #pragma unroll
  for (int rg=0;rg<4;rg++)
    #pragma unroll
    for (int r=0;r<4;r++) fv[rg][r] = frl[rg*16 + (lane>>4)*4 + r];
  #pragma unroll
  for (int nt=0;nt<4;nt++){
    int n = w*64 + nt*16 + (lane&15);
    float rw = rms_s[n];
    #pragma unroll
    for (int rg=0;rg<4;rg++)
      #pragma unroll
      for (int r=0;r<4;r++){
        int rowl = rg*16 + (lane>>4)*4 + r;
        *(unsigned short*)(oLDS + osw(rowl, n*2)) = f2bf(oa[rg*4+nt][r] * fv[rg][r] * rw);
      }
  }
  __syncthreads();
  // coalesced gate pass: o2 = o_n * swish_g (precomputed), in-place over g half
  #pragma unroll
  for (int it=0; it<8; ++it){
    int task = it*256 + tid;
    int rowl = task >> 5, c8 = (task & 31)*8;
    size_t gbase = (size_t)(bb*NT + cs + rowl)*VGS + 1024 + hh*NHV + c8;
    short8 g8 = *(const short8*)(vgb + gbase);
    short8 o8 = *(const short8*)(oLDS + osw(rowl, c8*2));
    short8 out;
    #pragma unroll
    for (int e=0;e<8;e++)
      out[e] = (short)f2bf(bf2f((unsigned short)o8[e]) * bf2f((unsigned short)g8[e]));
    *(short8*)(vgb + gbase) = out;
  }
}

// ---------------- launch ----------------
extern "C" void kernel_launch(void* const* d_in, const int* in_sizes, int n_in,
                              void* d_out, int out_size, void* d_ws, size_t ws_size,
                              hipStream_t stream) {
  (void)in_sizes; (void)n_in; (void)out_size;
  const float* hs  = (const float*)d_in[0];
  const float* Wq  = (const float*)d_in[1];
  const float* Wk  = (const float*)d_in[2];
  const float* Wv  = (const float*)d_in[3];
  const float* Wa  = (const float*)d_in[4];
  const float* Wg  = (const float*)d_in[5];
  const float* Wo  = (const float*)d_in[6];
  const float* Al  = (const float*)d_in[7];
  const float* dtb = (const float*)d_in[8];
  const float* rmsw= (const float*)d_in[9];
  char* ws = (char*)d_ws;

  // workspace layout — total stays within known-safe 176,947,200 B
  constexpr size_t MB = 1048576;
  constexpr size_t OFF_QK   = 0;            // 32MB bf16 merged q|k  [16384][1024]
  constexpr size_t OFF_VG   = 32*MB;        // 64MB bf16 merged v|swish(g) [16384][2048]
  constexpr size_t OFF_WQKH = 96*MB;        // 2MB concat [wq^T; wk^T] hi
  constexpr size_t OFF_WQKL = 98*MB;        // 2MB concat [wq^T; wk^T] lo
  constexpr size_t OFF_WVG  = 100*MB;       // 4MB concat [wv^T; wg^T]
  constexpr size_t OFF_WO   = 104*MB;       // 2MB
  constexpr size_t OFF_GC   = 106*MB;                 // 256KB
  constexpr size_t OFF_GD   = 106*MB + 262144;        // 512KB
  constexpr size_t OFF_SBC  = 107*MB;       // 64MB bf16 chunk states; hsh aliases pre-phaseA
  constexpr size_t WS_REQUIRED = 176947200;
  if (ws_size < WS_REQUIRED) return;

  unsigned short* qkb  = (unsigned short*)(ws + OFF_QK);
  unsigned short* vgb  = (unsigned short*)(ws + OFF_VG);
  unsigned short* wqkh = (unsigned short*)(ws + OFF_WQKH);
  unsigned short* wqkl = (unsigned short*)(ws + OFF_WQKL);
  unsigned short* wvgt = (unsigned short*)(ws + OFF_WVG);
  unsigned short* wot  = (unsigned short*)(ws + OFF_WO);
  float* Gc   = (float*)(ws + OFF_GC);
  double* Gd  = (double*)(ws + OFF_GD);
  unsigned short* Sbc = (unsigned short*)(ws + OFF_SBC);
  unsigned short* hsh = (unsigned short*)(ws + OFF_SBC);          // 32MB, dead before phaseA

  // fused prep: alphacast (blocks 0..16383) + LDS-tiled weight transposes (16384..17407)
  k_prep<<<17408, 256, 0, stream>>>(hs, Wa, Al, dtb, Gc, hsh,
                                    Wq, Wk, Wv, Wg, Wo, wqkh, wqkl, wvgt, wot);

  // projections: merged q|k 2-pass (B hi+lo); merged v|g single-pass with swish on g half
  k_gemm2<1,0><<<dim3(128,8), 256, 0, stream>>>(hsh, wqkh, wqkl, qkb, 16384, 1024, 1024);
  k_gemm2<0,2><<<dim3(128,16), 256, 0, stream>>>(hsh, wvgt, nullptr, vgb, 16384, 2048, 1024);

  k_cumsum<<<8, 256, 0, stream>>>(Gc, Gd);

  k_phaseA<<<dim3(NCHK,8,2), 256, 0, stream>>>(qkb, vgb, Gd, Sbc);
  k_phaseB<<<dim3(32,8), 256, 0, stream>>>(Sbc, Gd);
  k_phaseC<<<dim3(NCHK,8), 256, 0, stream>>>(qkb, vgb, rmsw, Gd, Sbc);

  // final GEMM: o2 (= g half of vgb, lda 2048) @ Wo^T
  k_gemm<<<dim3(128,8), 256, 0, stream>>>(vgb + 1024, wot, (float*)d_out, 16384, 1024, 1024, VGS);
}

// Round 29
// 381.020 us; speedup vs baseline: 1.0340x; 1.0265x over previous
//
#include <hip/hip_runtime.h>
#include <cstdint>
#include <cstddef>

// Problem constants
#define NB 2
#define NT 8192
#define ND 1024
#define NH 4
#define NV 1024
#define NHV 256
#define NHK 128
#define CHK 64
#define NCHK 128            // chunks per (b,h)
#define QKS 1024            // merged q|k row stride
#define VGS 2048            // merged v|g row stride
#define SCALE 0.08838834764831845f   // HK^-0.5

using f32x4 = __attribute__((ext_vector_type(4))) float;
using short8 = __attribute__((ext_vector_type(8))) short;
using s16x4 = __attribute__((ext_vector_type(4))) short;

__device__ __forceinline__ float bf2f(unsigned short u){
  union { unsigned int i; float f; } t; t.i = ((unsigned int)u) << 16; return t.f;
}
__device__ __forceinline__ unsigned short f2bf(float f){
  union { float f; unsigned int i; } t; t.f = f;
  unsigned int r = t.i + 0x7fffu + ((t.i >> 16) & 1u);
  return (unsigned short)(r >> 16);
}
__device__ __forceinline__ double shfl_up_dbl(double v, int off){
  union { double d; unsigned int u[2]; } a, r;
  a.d = v;
  r.u[0] = __shfl_up(a.u[0], off, 64);
  r.u[1] = __shfl_up(a.u[1], off, 64);
  return r.d;
}
// Swizzled LDS accessor for bf16 tiles: row-major, rowBytes in {128,256}.
__device__ __forceinline__ void* lds_at(void* base, int row, int colElem, int rowBytes){
  return (void*)((char*)base + row*rowBytes + (((colElem*2) ^ ((row&7)<<4))));
}
// swizzle for the [64][256] bf16 o-tile (512B rows)
__device__ __forceinline__ int osw(int rowl, int byteoff){
  return rowl*512 + (byteoff ^ (((rowl>>2)&7)<<4));
}
// XCD-chunked, A-panel-major block swizzle. total = gx*gy must be %8==0.
__device__ __forceinline__ void xcd_swizzle(int gx, int gy, int& bx, int& by){
  int flat = blockIdx.y*gx + blockIdx.x;
  int total = gx*gy;
  int wg = (flat & 7)*(total >> 3) + (flat >> 3);
  bx = wg / gy;
  by = wg % gy;
}

// ---- async global->LDS, 16B per lane; dest is wave-uniform base + lane*16 (m97 pattern) ----
typedef const __attribute__((address_space(1))) unsigned int as1_u32;
typedef __attribute__((address_space(3))) unsigned int as3_u32;
__device__ __forceinline__ void gl_lds16(const void* g_lane, void* lds_uniform){
  __builtin_amdgcn_global_load_lds((as1_u32*)(uintptr_t)g_lane,
                                   (as3_u32*)(unsigned int)(uintptr_t)lds_uniform,
                                   16, 0, 0);
}

// ---- fused prep: blocks 0..16383 = alphacast; 16384..17407 = LDS-tiled weight transposes ----
__global__ __launch_bounds__(256) void k_prep(const float* __restrict__ hs,
                                              const float* __restrict__ Wa,
                                              const float* __restrict__ Al,
                                              const float* __restrict__ dtb,
                                              float* __restrict__ Gc,
                                              unsigned short* __restrict__ hsh,
                                              const float* __restrict__ Wq,
                                              const float* __restrict__ Wk,
                                              const float* __restrict__ Wv,
                                              const float* __restrict__ Wg,
                                              const float* __restrict__ Wo,
                                              unsigned short* __restrict__ wqkh,
                                              unsigned short* __restrict__ wqkl,
                                              unsigned short* __restrict__ wvgt,
                                              unsigned short* __restrict__ wot){
  int b = blockIdx.x, tid = threadIdx.x;
  if (b < 16384){
    // ---- alphacast: cast hs row to bf16 + alpha = hs@Wa -> gk (pre-cumsum, exact fp32) ----
    int rowi = b;
    const float* h = hs + (size_t)rowi*ND;
    f32x4 x = *(const f32x4*)(h + tid*4);
    s16x4 hb;
    #pragma unroll
    for (int e=0;e<4;e++) hb[e] = (short)f2bf(x[e]);
    *(s16x4*)(hsh + (size_t)rowi*ND + tid*4) = hb;
    float a0=0.f,a1=0.f,a2=0.f,a3=0.f;
    #pragma unroll
    for (int e=0;e<4;e++){
      int d = tid*4+e;
      a0 += x[e]*Wa[d*4+0]; a1 += x[e]*Wa[d*4+1]; a2 += x[e]*Wa[d*4+2]; a3 += x[e]*Wa[d*4+3];
    }
    #pragma unroll
    for (int off=32; off>0; off>>=1){
      a0 += __shfl_down(a0, off, 64); a1 += __shfl_down(a1, off, 64);
      a2 += __shfl_down(a2, off, 64); a3 += __shfl_down(a3, off, 64);
    }
    __shared__ float red[4][4];
    if ((tid&63)==0){ int w = tid>>6; red[w][0]=a0; red[w][1]=a1; red[w][2]=a2; red[w][3]=a3; }
    __syncthreads();
    if (tid < 4){
      float al = red[0][tid]+red[1][tid]+red[2][tid]+red[3][tid];
      float xx = al + dtb[tid];
      float sp = (xx > 20.f) ? xx : log1pf(expf(xx));
      float gkv = -expf(Al[tid]) * sp;
      int bb = rowi >> 13, t = rowi & (NT-1);
      Gc[((size_t)(bb*NH + tid))*NT + t] = gkv;
    }
  } else {
    // ---- LDS-tiled 64x64 transpose: coalesced reads AND writes ----
    __shared__ float tile[64][65];
    int b2 = b - 16384;
    const float* src; int C; int rt, ct; int hilo = 0; size_t boff = 0;
    unsigned short *dsth = nullptr, *dstl = nullptr;
    if (b2 < 128){          src = Wq; C = 512;  rt = b2 >> 3;          ct = b2 & 7;  hilo = 1; boff = 0;          dsth = wqkh; dstl = wqkl; }
    else if (b2 < 256){     src = Wk; C = 512;  rt = (b2-128) >> 3;    ct = (b2-128) & 7;  hilo = 1; boff = 512*1024;  dsth = wqkh; dstl = wqkl; }
    else if (b2 < 512){     src = Wv; C = 1024; rt = (b2-256) >> 4;    ct = (b2-256) & 15; boff = 0;          dsth = wvgt; }
    else if (b2 < 768){     src = Wg; C = 1024; rt = (b2-512) >> 4;    ct = (b2-512) & 15; boff = 1024*1024; dsth = wvgt; }
    else {                  src = Wo; C = 1024; rt = (b2-768) >> 4;    ct = (b2-768) & 15; boff = 0;          dsth = wot;  }
    int r0 = rt*64, c0 = ct*64;
    #pragma unroll
    for (int it=0; it<16; ++it){
      int r = it*4 + (tid>>6);
      int c = tid & 63;
      tile[r][c] = src[(size_t)(r0+r)*C + c0 + c];
    }
    __syncthreads();
    #pragma unroll
    for (int it=0; it<16; ++it){
      int c = it*4 + (tid>>6);
      int r = tid & 63;
      float x = tile[r][c];
      unsigned short h = f2bf(x);
      dsth[boff + (size_t)(c0+c)*1024 + r0 + r] = h;
      if (hilo) dstl[boff + (size_t)(c0+c)*1024 + r0 + r] = f2bf(x - bf2f(h));
    }
  }
}

// --- qk GEMM (B hi+lo, 2-pass) with fused fp64 cumsum in grid row by==8 ---
// grid (128, 9): by<8 -> GEMM block (swizzle over literal 128x8, identical mapping to the
// standalone version); by==8 && bx<8 -> 3-phase cumsum for bh=bx (needs only Gc from k_prep,
// must complete before phaseA -- guaranteed by stream order). Removes a serial 8-block dispatch.
__global__ __launch_bounds__(256, 3)
void k_gemmQK(const unsigned short* __restrict__ A2h,
              const unsigned short* __restrict__ Bth,
              const unsigned short* __restrict__ Btl,
              unsigned short* __restrict__ C, int M, int N, int K,
              const float* __restrict__ Gc, double* __restrict__ Gd){
  __shared__ unsigned short sA[2][4096];
  __shared__ unsigned short sB[2][4096];
  __shared__ unsigned short sBl[2][4096];
  __shared__ double wsum[4];
  int tid = threadIdx.x, lane = tid & 63, wave = tid >> 6;
  if (blockIdx.y == 8){
    if (blockIdx.x >= 8) return;
    int bh = blockIdx.x;
    const float* g = Gc + (size_t)bh*NT;
    double* out = Gd + (size_t)bh*NT;
    double tot = 0.0;
    #pragma unroll
    for (int i=0;i<32;i++) tot += (double)g[tid*32 + i];
    double v = tot;
    #pragma unroll
    for (int off=1; off<64; off<<=1){
      double y = shfl_up_dbl(v, off);
      if (lane >= off) v += y;
    }
    if (lane == 63) wsum[wave] = v;
    __syncthreads();
    double add = 0.0;
    for (int w2=0; w2<wave; ++w2) add += wsum[w2];
    double run = (v - tot) + add;      // exclusive prefix for this thread
    #pragma unroll
    for (int i=0;i<32;i++){
      run += (double)g[tid*32 + i];
      out[tid*32 + i] = run;
    }
    return;
  }
  int bx, by;
  xcd_swizzle(128, 8, bx, by);         // literals: mapping identical to standalone (128,8) grid
  int m0 = bx*128, n0 = by*128;
  int wr = (wave>>1)*64, wc = (wave&1)*64;
  int row = lane & 15, kq = (lane>>4)*8;
  int rS = lane>>2, cS = (lane&3)*8;
  f32x4 acc[4][4];
  #pragma unroll
  for (int m=0;m<4;m++)
    #pragma unroll
    for (int n=0;n<4;n++)
      #pragma unroll
      for (int r=0;r<4;r++) acc[m][n][r] = 0.f;

  auto STAGE = [&](int buf, int k0){
    #pragma unroll
    for (int half=0; half<2; ++half){
      int rb = half*64 + wave*16;
      size_t gArow = (size_t)(m0 + rb + rS)*K + k0 + cS;
      size_t gBrow = (size_t)(n0 + rb + rS)*K + k0 + cS;
      gl_lds16(A2h + gArow, &sA[buf][rb*32]);
      gl_lds16(Bth + gBrow, &sB[buf][rb*32]);
      gl_lds16(Btl + gBrow, &sBl[buf][rb*32]);
    }
  };

  STAGE(0, 0);
  __syncthreads();
  int nsteps = K >> 5;
  for (int t=0; t<nsteps; ++t){
    int cur = t & 1;
    if (t+1 < nsteps) STAGE(cur^1, (t+1)*32);
    short8 ah[4], bh8[4];
    #pragma unroll
    for (int m=0;m<4;m++) ah[m] = *(const short8*)(&sA[cur][(wr + m*16 + row)*32 + kq]);
    #pragma unroll
    for (int n=0;n<4;n++) bh8[n] = *(const short8*)(&sB[cur][(wc + n*16 + row)*32 + kq]);
    #pragma unroll
    for (int m=0;m<4;m++)
      #pragma unroll
      for (int n=0;n<4;n++)
        acc[m][n] = __builtin_amdgcn_mfma_f32_16x16x32_bf16(ah[m], bh8[n], acc[m][n], 0, 0, 0);
    {
      short8 bl[4];
      #pragma unroll
      for (int n=0;n<4;n++) bl[n] = *(const short8*)(&sBl[cur][(wc + n*16 + row)*32 + kq]);
      #pragma unroll
      for (int m=0;m<4;m++)
        #pragma unroll
        for (int n=0;n<4;n++)
          acc[m][n] = __builtin_amdgcn_mfma_f32_16x16x32_bf16(ah[m], bl[n], acc[m][n], 0, 0, 0);
    }
    __syncthreads();
  }
  #pragma unroll
  for (int m=0;m<4;m++)
    #pragma unroll
    for (int n=0;n<4;n++)
      #pragma unroll
      for (int r=0;r<4;r++){
        int rr = m0 + wr + m*16 + (lane>>4)*4 + r;
        int cc = n0 + wc + n*16 + (lane&15);
        C[(size_t)rr*N + cc] = f2bf(acc[m][n][r]);
      }
}

// --- 2-phase dbuf GEMM: C = A@Bth^T; GSWISH==2 -> swish where n0 >= 1024 (merged v|g) ---
template<int GSWISH>
__global__ __launch_bounds__(256, 4)
void k_gemm2(const unsigned short* __restrict__ A2h,
             const unsigned short* __restrict__ Bth,
             unsigned short* __restrict__ C, int M, int N, int K){
  __shared__ unsigned short sA[2][4096];
  __shared__ unsigned short sB[2][4096];
  int tid = threadIdx.x, lane = tid & 63, wave = tid >> 6;
  int bx, by;
  xcd_swizzle(gridDim.x, gridDim.y, bx, by);
  int m0 = bx*128, n0 = by*128;
  int wr = (wave>>1)*64, wc = (wave&1)*64;
  int row = lane & 15, kq = (lane>>4)*8;
  int rS = lane>>2, cS = (lane&3)*8;
  f32x4 acc[4][4];
  #pragma unroll
  for (int m=0;m<4;m++)
    #pragma unroll
    for (int n=0;n<4;n++)
      #pragma unroll
      for (int r=0;r<4;r++) acc[m][n][r] = 0.f;

  auto STAGE = [&](int buf, int k0){
    #pragma unroll
    for (int half=0; half<2; ++half){
      int rb = half*64 + wave*16;
      size_t gArow = (size_t)(m0 + rb + rS)*K + k0 + cS;
      size_t gBrow = (size_t)(n0 + rb + rS)*K + k0 + cS;
      gl_lds16(A2h + gArow, &sA[buf][rb*32]);
      gl_lds16(Bth + gBrow, &sB[buf][rb*32]);
    }
  };

  STAGE(0, 0);
  __syncthreads();
  int nsteps = K >> 5;
  for (int t=0; t<nsteps; ++t){
    int cur = t & 1;
    if (t+1 < nsteps) STAGE(cur^1, (t+1)*32);
    short8 ah[4], bh[4];
    #pragma unroll
    for (int m=0;m<4;m++) ah[m] = *(const short8*)(&sA[cur][(wr + m*16 + row)*32 + kq]);
    #pragma unroll
    for (int n=0;n<4;n++) bh[n] = *(const short8*)(&sB[cur][(wc + n*16 + row)*32 + kq]);
    #pragma unroll
    for (int m=0;m<4;m++)
      #pragma unroll
      for (int n=0;n<4;n++)
        acc[m][n] = __builtin_amdgcn_mfma_f32_16x16x32_bf16(ah[m], bh[n], acc[m][n], 0, 0, 0);
    __syncthreads();
  }
  bool dosw = (GSWISH == 2) && (n0 >= 1024);
  #pragma unroll
  for (int m=0;m<4;m++)
    #pragma unroll
    for (int n=0;n<4;n++)
      #pragma unroll
      for (int r=0;r<4;r++){
        int rr = m0 + wr + m*16 + (lane>>4)*4 + r;
        int cc = n0 + wc + n*16 + (lane&15);
        float v = acc[m][n][r];
        if (dosw) v = v / (1.f + expf(-v));
        C[(size_t)rr*N + cc] = f2bf(v);
      }
}

// ---------------- final GEMM (fp32 out), dbuf prefetch, strided A ----------------
__global__ __launch_bounds__(256, 4) void k_gemm(const unsigned short* __restrict__ A,
                                                 const unsigned short* __restrict__ Bt,
                                                 float* __restrict__ C, int M, int N, int K,
                                                 int lda){
  __shared__ unsigned short sA[2][4096];
  __shared__ unsigned short sB[2][4096];
  int tid = threadIdx.x, lane = tid & 63, wave = tid >> 6;
  int bx, by;
  xcd_swizzle(gridDim.x, gridDim.y, bx, by);
  int m0 = bx*128, n0 = by*128;
  int wr = (wave>>1)*64, wc = (wave&1)*64;
  int row = lane & 15, kq = (lane>>4)*8;
  int rS = lane>>2, cS = (lane&3)*8;
  f32x4 acc[4][4];
  #pragma unroll
  for (int m=0;m<4;m++)
    #pragma unroll
    for (int n=0;n<4;n++)
      #pragma unroll
      for (int r=0;r<4;r++) acc[m][n][r] = 0.f;

  auto STAGE = [&](int buf, int k0){
    #pragma unroll
    for (int half=0; half<2; ++half){
      int rb = half*64 + wave*16;
      size_t gArow = (size_t)(m0 + rb + rS)*lda + k0 + cS;
      size_t gBrow = (size_t)(n0 + rb + rS)*K + k0 + cS;
      gl_lds16(A  + gArow, &sA[buf][rb*32]);
      gl_lds16(Bt + gBrow, &sB[buf][rb*32]);
    }
  };

  STAGE(0, 0);
  __syncthreads();
  int nsteps = K >> 5;
  for (int t=0; t<nsteps; ++t){
    int cur = t & 1;
    if (t+1 < nsteps) STAGE(cur^1, (t+1)*32);
    short8 af[4], bfr[4];
    #pragma unroll
    for (int m=0;m<4;m++) af[m]  = *(const short8*)(&sA[cur][(wr + m*16 + row)*32 + kq]);
    #pragma unroll
    for (int n=0;n<4;n++) bfr[n] = *(const short8*)(&sB[cur][(wc + n*16 + row)*32 + kq]);
    #pragma unroll
    for (int m=0;m<4;m++)
      #pragma unroll
      for (int n=0;n<4;n++)
        acc[m][n] = __builtin_amdgcn_mfma_f32_16x16x32_bf16(af[m], bfr[n], acc[m][n], 0, 0, 0);
    __syncthreads();
  }
  #pragma unroll
  for (int m=0;m<4;m++)
    #pragma unroll
    for (int n=0;n<4;n++)
      #pragma unroll
      for (int r=0;r<4;r++){
        int rr = m0 + wr + m*16 + (lane>>4)*4 + r;
        int cc = n0 + wc + n*16 + (lane&15);
        C[(size_t)rr*N + cc] = acc[m][n][r];
      }
}

// ---- phase A (MFMA, per-chunk, n-split z=2): S_loc^T[n][k] = sum_j exp(Gend-Gj) v_j k_j ----
__global__ __launch_bounds__(256, 3) void k_phaseA(const unsigned short* __restrict__ qkb,
                                                   const unsigned short* __restrict__ vgb,
                                                   const double* __restrict__ Gd,
                                                   unsigned short* __restrict__ Sbc){
  __shared__ unsigned short vT[8192];    // [128 n][64 j] swizzled (this z-half)
  __shared__ unsigned short wkT[8192];   // [128 k][64 j] swizzled
  int blk = blockIdx.x, bh = blockIdx.y, z = blockIdx.z;
  int bb = bh>>2, hh = bh&3;
  int cs = blk*CHK, tid = threadIdx.x;
  int lane = tid & 63, w = tid >> 6;
  const double* Gb = Gd + (size_t)bh*NT;
  double Gend = Gb[cs + 63];
  #pragma unroll
  for (int it=0; it<4; ++it){
    int task = it*256 + tid;
    int j = task & 63, ng = task >> 6;   // ng in 0..15
    short8 vv = *(const short8*)(vgb + (size_t)(bb*NT + cs + j)*VGS + hh*NHV + z*128 + ng*8);
    #pragma unroll
    for (int e=0;e<8;e++)
      *(unsigned short*)lds_at(vT, ng*8+e, j, 128) = (unsigned short)vv[e];
  }
  #pragma unroll
  for (int it=0; it<4; ++it){
    int task = it*256 + tid;
    int j = task & 63, kg = task >> 6;
    float wj = expf((float)(Gend - Gb[cs + j]));
    short8 kv = *(const short8*)(qkb + (size_t)(bb*NT + cs + j)*QKS + 512 + hh*NHK + kg*8);
    #pragma unroll
    for (int e=0;e<8;e++)
      *(unsigned short*)lds_at(wkT, kg*8+e, j, 128) = f2bf(wj * bf2f((unsigned short)kv[e]));
  }
  __syncthreads();
  f32x4 sa[16];
  #pragma unroll
  for (int i=0;i<16;i++) sa[i] = (f32x4){0.f,0.f,0.f,0.f};
  short8 wa[2][2];
  #pragma unroll
  for (int mt=0;mt<2;mt++)
    #pragma unroll
    for (int kk=0;kk<2;kk++)
      wa[mt][kk] = *(short8*)lds_at(wkT, 32*w + mt*16 + (lane&15), kk*32 + (lane>>4)*8, 128);
  #pragma unroll
  for (int mt=0;mt<2;mt++)
    #pragma unroll
    for (int nt=0;nt<8;nt++)
      #pragma unroll
      for (int kk=0;kk<2;kk++){
        short8 b = *(short8*)lds_at(vT, nt*16 + (lane&15), kk*32 + (lane>>4)*8, 128);
        sa[mt*8+nt] = __builtin_amdgcn_mfma_f32_16x16x32_bf16(wa[mt][kk], b, sa[mt*8+nt], 0,0,0);
      }
  unsigned short* dst = Sbc + (size_t)(bh*NCHK + blk)*32768 + (size_t)z*16384;
  #pragma unroll
  for (int mt=0;mt<2;mt++)
    #pragma unroll
    for (int nt=0;nt<8;nt++){
      int k = 32*w + mt*16 + (lane>>4)*4;
      int n = nt*16 + (lane&15);
      s16x4 p;
      #pragma unroll
      for (int r=0;r<4;r++) p[r] = (short)f2bf(sa[mt*8+nt][r]);
      *(s16x4*)(dst + (size_t)n*128 + k) = p;
    }
}

// ---------------- phase B: parallel elementwise scan, 4-deep prefetch ----------------
__global__ __launch_bounds__(256) void k_phaseB(unsigned short* __restrict__ Sbc,
                                                const double* __restrict__ Gd){
  int slice = blockIdx.x, bh = blockIdx.y;
  int tid = threadIdx.x;
  const double* Gb = Gd + (size_t)bh*NT;
  unsigned short* base = Sbc + (size_t)(bh*NCHK)*32768 + slice*1024 + tid*4;
  s16x4 c0 = *(const s16x4*)(base);
  f32x4 run;
  #pragma unroll
  for (int e=0;e<4;e++) run[e] = bf2f((unsigned short)c0[e]);
  s16x4 n0 = *(const s16x4*)(base + (size_t)1*32768);
  s16x4 n1 = *(const s16x4*)(base + (size_t)2*32768);
  s16x4 n2 = *(const s16x4*)(base + (size_t)3*32768);
  s16x4 n3 = *(const s16x4*)(base + (size_t)4*32768);
#define PB_STEP(U, BB) \
  { float resc = expf((float)(Gb[(BB)*CHK + 63] - Gb[(BB)*CHK - 1])); \
    s16x4 o_; \
    _Pragma("unroll") \
    for (int e=0;e<4;e++){ run[e] = resc*run[e] + bf2f((unsigned short)U[e]); o_[e] = (short)f2bf(run[e]); } \
    *(s16x4*)(base + (size_t)(BB)*32768) = o_; }
  for (int b=1; b<NCHK; b+=4){
    s16x4 u0=n0, u1=n1, u2=n2, u3=n3;
    if (b+4 < NCHK) n0 = *(const s16x4*)(base + (size_t)(b+4)*32768);
    if (b+5 < NCHK) n1 = *(const s16x4*)(base + (size_t)(b+5)*32768);
    if (b+6 < NCHK) n2 = *(const s16x4*)(base + (size_t)(b+6)*32768);
    if (b+7 < NCHK) n3 = *(const s16x4*)(base + (size_t)(b+7)*32768);
    PB_STEP(u0, b)
    if (b+1 < NCHK) PB_STEP(u1, b+1)
    if (b+2 < NCHK) PB_STEP(u2, b+2)
    if (b+3 < NCHK) PB_STEP(u3, b+3)
  }
#undef PB_STEP
}

// ---- phase C: o_inter hoisted pre-barrier; gate uses precomputed swish(g) ----
__global__ __launch_bounds__(256, 3) void k_phaseC(const unsigned short* __restrict__ qkb,
                                                   unsigned short* __restrict__ vgb,   // v cols 0-1023, swish(g) cols 1024+
                                                   const float* __restrict__ rmsw,
                                                   const double* __restrict__ Gd,
                                                   const unsigned short* __restrict__ Sbc){
  __shared__ unsigned short vT[16384];   // [256 n][64 j] swz; reused as o-tile [64][256]
  __shared__ unsigned short scp[4096];   // [64][64] swz
  __shared__ float Gsf[64];
  __shared__ float sI[64];               // SCALE*exp(Gsf)
  __shared__ float rsum[64][4];
  __shared__ float frl[64];
  __shared__ float rms_s[256];
  int blk = blockIdx.x, bh = blockIdx.y;
  int bb = bh>>2, hh = bh&3;
  int cs = blk*CHK, tid = threadIdx.x;
  int lane = tid&63, w = tid>>6;
  const double* Gb = Gd + (size_t)bh*NT;
  // tables
  rms_s[tid] = rmsw[tid];
  if (tid < 64){
    double ref = (cs == 0) ? 0.0 : Gb[cs-1];
    float g = (float)(Gb[cs+tid] - ref);
    Gsf[tid] = g;
    sI[tid] = SCALE * expf(g);
  }
  // stage vT (reg-staged transpose scatter)
  #pragma unroll
  for (int it=0; it<8; ++it){
    int task = it*256 + tid;
    int j = task & 63, ng = task >> 6;
    short8 vv = *(const short8*)(vgb + (size_t)(bb*NT + cs + j)*VGS + hh*NHV + ng*8);
    #pragma unroll
    for (int e=0;e<8;e++)
      *(unsigned short*)lds_at(vT, ng*8+e, j, 128) = (unsigned short)vv[e];
  }
  // o_inter BEFORE the barrier (no LDS deps): q,S from global, overlaps vT staging
  f32x4 oa[16];   // [rg*4 + nt]
  #pragma unroll
  for (int i=0;i<16;i++) oa[i] = (f32x4){0.f,0.f,0.f,0.f};
  if (blk > 0){
    const unsigned short* Sst = Sbc + (size_t)(bh*NCHK + blk - 1)*32768;
    #pragma unroll
    for (int kk=0;kk<4;kk++){
      short8 qrg[4];
      #pragma unroll
      for (int rg=0;rg<4;rg++)
        qrg[rg] = *(const short8*)(qkb + (size_t)(bb*NT + cs + rg*16 + (lane&15))*QKS
                                   + hh*NHK + kk*32 + (lane>>4)*8);
      #pragma unroll
      for (int nt=0;nt<4;nt++){
        short8 b = *(const short8*)(Sst + (size_t)(w*64 + nt*16 + (lane&15))*128
                                    + kk*32 + (lane>>4)*8);
        #pragma unroll
        for (int rg=0;rg<4;rg++)
          oa[rg*4+nt] = __builtin_amdgcn_mfma_f32_16x16x32_bf16(qrg[rg], b, oa[rg*4+nt], 0,0,0);
      }
    }
  }
  __syncthreads();   // vT + Gsf/sI/rms_s visible
  if (blk > 0){
    #pragma unroll
    for (int rg=0;rg<4;rg++)
      #pragma unroll
      for (int r=0;r<4;r++){
        float srow = sI[rg*16 + (lane>>4)*4 + r];
        #pragma unroll
        for (int nt=0;nt<4;nt++) oa[rg*4+nt][r] *= srow;
      }
  }
  // P for own row-group
  f32x4 pa[4];
  #pragma unroll
  for (int jt=0;jt<4;jt++) pa[jt] = (f32x4){0.f,0.f,0.f,0.f};
  {
    short8 qown[4];
    #pragma unroll
    for (int kk=0;kk<4;kk++)
      qown[kk] = *(const short8*)(qkb + (size_t)(bb*NT + cs + 16*w + (lane&15))*QKS
                                  + hh*NHK + kk*32 + (lane>>4)*8);
    #pragma unroll
    for (int jt=0;jt<4;jt++)
      #pragma unroll
      for (int kk=0;kk<4;kk++){
        short8 b = *(const short8*)(qkb + (size_t)(bb*NT + cs + jt*16 + (lane&15))*QKS
                                    + 512 + hh*NHK + kk*32 + (lane>>4)*8);
        pa[jt] = __builtin_amdgcn_mfma_f32_16x16x32_bf16(qown[kk], b, pa[jt], 0,0,0);
      }
  }
  // weight + causal mask -> scp (bf16)
  #pragma unroll
  for (int jt=0;jt<4;jt++)
    #pragma unroll
    for (int r=0;r<4;r++){
      int il = 16*w + (lane>>4)*4 + r;
      int jl = jt*16 + (lane&15);
      float wgt = (jl <= il) ? SCALE * expf(Gsf[il] - Gsf[jl]) : 0.f;
      *(unsigned short*)lds_at(scp, il, jl, 128) = f2bf(wgt * pa[jt][r]);
    }
  __syncthreads();   // scp written by all waves
  // PV: A = scp rows (all 4 row-groups), B = vT n-slice
  short8 af[4][2];
  #pragma unroll
  for (int rg=0;rg<4;rg++)
    #pragma unroll
    for (int kk=0;kk<2;kk++)
      af[rg][kk] = *(short8*)lds_at(scp, rg*16 + (lane&15), kk*32 + (lane>>4)*8, 128);
  #pragma unroll
  for (int nt=0;nt<4;nt++){
    short8 b0 = *(short8*)lds_at(vT, w*64 + nt*16 + (lane&15), 0*32 + (lane>>4)*8, 128);
    short8 b1 = *(short8*)lds_at(vT, w*64 + nt*16 + (lane&15), 1*32 + (lane>>4)*8, 128);
    #pragma unroll
    for (int rg=0;rg<4;rg++){
      oa[rg*4+nt] = __builtin_amdgcn_mfma_f32_16x16x32_bf16(af[rg][0], b0, oa[rg*4+nt], 0,0,0);
      oa[rg*4+nt] = __builtin_amdgcn_mfma_f32_16x16x32_bf16(af[rg][1], b1, oa[rg*4+nt], 0,0,0);
    }
  }
  // RMS partials over this wave's 64 cols, then cross-wave reduce
  float pp[16];
  #pragma unroll
  for (int rg=0;rg<4;rg++)
    #pragma unroll
    for (int r=0;r<4;r++){
      float s = 0.f;
      #pragma unroll
      for (int nt=0;nt<4;nt++) s += oa[rg*4+nt][r]*oa[rg*4+nt][r];
      pp[rg*4+r] = s;
    }
  #pragma unroll
  for (int i=0;i<16;i++){
    #pragma unroll
    for (int off=1; off<16; off<<=1) pp[i] += __shfl_xor(pp[i], off, 16);
  }
  if ((lane&15) == 0){
    int l4 = lane>>4;
    #pragma unroll
    for (int rg=0;rg<4;rg++)
      #pragma unroll
      for (int r=0;r<4;r++)
        rsum[rg*16 + l4*4 + r][w] = pp[rg*4+r];
  }
  __syncthreads();   // also: all waves done reading vT (PV complete)
  if (tid < 64)
    frl[tid] = rsqrtf((rsum[tid][0]+rsum[tid][1]+rsum[tid][2]+rsum[tid][3])*(1.f/256.f) + 1e-5f);
  __syncthreads();
  // write normalized o into oLDS (vT reused)
  char* oLDS = (char*)vT;
  float fv[4][4];
  #pragma unroll
  for (int rg=0;rg<4;rg++)
    #pragma unroll
    for (int r=0;r<4;r++) fv[rg][r] = frl[rg*16 + (lane>>4)*4 + r];
  #pragma unroll
  for (int nt=0;nt<4;nt++){
    int n = w*64 + nt*16 + (lane&15);
    float rw = rms_s[n];
    #pragma unroll
    for (int rg=0;rg<4;rg++)
      #pragma unroll
      for (int r=0;r<4;r++){
        int rowl = rg*16 + (lane>>4)*4 + r;
        *(unsigned short*)(oLDS + osw(rowl, n*2)) = f2bf(oa[rg*4+nt][r] * fv[rg][r] * rw);
      }
  }
  __syncthreads();
  // coalesced gate pass: o2 = o_n * swish_g (precomputed), in-place over g half
  #pragma unroll
  for (int it=0; it<8; ++it){
    int task = it*256 + tid;
    int rowl = task >> 5, c8 = (task & 31)*8;
    size_t gbase = (size_t)(bb*NT + cs + rowl)*VGS + 1024 + hh*NHV + c8;
    short8 g8 = *(const short8*)(vgb + gbase);
    short8 o8 = *(const short8*)(oLDS + osw(rowl, c8*2));
    short8 out;
    #pragma unroll
    for (int e=0;e<8;e++)
      out[e] = (short)f2bf(bf2f((unsigned short)o8[e]) * bf2f((unsigned short)g8[e]));
    *(short8*)(vgb + gbase) = out;
  }
}

// ---------------- launch ----------------
extern "C" void kernel_launch(void* const* d_in, const int* in_sizes, int n_in,
                              void* d_out, int out_size, void* d_ws, size_t ws_size,
                              hipStream_t stream) {
  (void)in_sizes; (void)n_in; (void)out_size;
  const float* hs  = (const float*)d_in[0];
  const float* Wq  = (const float*)d_in[1];
  const float* Wk  = (const float*)d_in[2];
  const float* Wv  = (const float*)d_in[3];
  const float* Wa  = (const float*)d_in[4];
  const float* Wg  = (const float*)d_in[5];
  const float* Wo  = (const float*)d_in[6];
  const float* Al  = (const float*)d_in[7];
  const float* dtb = (const float*)d_in[8];
  const float* rmsw= (const float*)d_in[9];
  char* ws = (char*)d_ws;

  // workspace layout — total stays within known-safe 176,947,200 B
  constexpr size_t MB = 1048576;
  constexpr size_t OFF_QK   = 0;            // 32MB bf16 merged q|k  [16384][1024]
  constexpr size_t OFF_VG   = 32*MB;        // 64MB bf16 merged v|swish(g) [16384][2048]
  constexpr size_t OFF_WQKH = 96*MB;        // 2MB concat [wq^T; wk^T] hi
  constexpr size_t OFF_WQKL = 98*MB;        // 2MB concat [wq^T; wk^T] lo
  constexpr size_t OFF_WVG  = 100*MB;       // 4MB concat [wv^T; wg^T]
  constexpr size_t OFF_WO   = 104*MB;       // 2MB
  constexpr size_t OFF_GC   = 106*MB;                 // 256KB
  constexpr size_t OFF_GD   = 106*MB + 262144;        // 512KB
  constexpr size_t OFF_SBC  = 107*MB;       // 64MB bf16 chunk states; hsh aliases pre-phaseA
  constexpr size_t WS_REQUIRED = 176947200;
  if (ws_size < WS_REQUIRED) return;

  unsigned short* qkb  = (unsigned short*)(ws + OFF_QK);
  unsigned short* vgb  = (unsigned short*)(ws + OFF_VG);
  unsigned short* wqkh = (unsigned short*)(ws + OFF_WQKH);
  unsigned short* wqkl = (unsigned short*)(ws + OFF_WQKL);
  unsigned short* wvgt = (unsigned short*)(ws + OFF_WVG);
  unsigned short* wot  = (unsigned short*)(ws + OFF_WO);
  float* Gc   = (float*)(ws + OFF_GC);
  double* Gd  = (double*)(ws + OFF_GD);
  unsigned short* Sbc = (unsigned short*)(ws + OFF_SBC);
  unsigned short* hsh = (unsigned short*)(ws + OFF_SBC);          // 32MB, dead before phaseA

  // fused prep: alphacast (blocks 0..16383) + LDS-tiled weight transposes (16384..17407)
  k_prep<<<17408, 256, 0, stream>>>(hs, Wa, Al, dtb, Gc, hsh,
                                    Wq, Wk, Wv, Wg, Wo, wqkh, wqkl, wvgt, wot);

  // qk projection (B hi+lo, 2-pass) with fused cumsum in grid row by==8
  k_gemmQK<<<dim3(128,9), 256, 0, stream>>>(hsh, wqkh, wqkl, qkb, 16384, 1024, 1024, Gc, Gd);
  // vg projection: single-pass with swish on g half
  k_gemm2<2><<<dim3(128,16), 256, 0, stream>>>(hsh, wvgt, vgb, 16384, 2048, 1024);

  k_phaseA<<<dim3(NCHK,8,2), 256, 0, stream>>>(qkb, vgb, Gd, Sbc);
  k_phaseB<<<dim3(32,8), 256, 0, stream>>>(Sbc, Gd);
  k_phaseC<<<dim3(NCHK,8), 256, 0, stream>>>(qkb, vgb, rmsw, Gd, Sbc);

  // final GEMM: o2 (= g half of vgb, lda 2048) @ Wo^T
  k_gemm<<<dim3(128,8), 256, 0, stream>>>(vgb + 1024, wot, (float*)d_out, 16384, 1024, 1024, VGS);
}